// Round 5
// baseline (613.735 us; speedup 1.0000x reference)
//
#include <hip/hip_runtime.h>
#include <cfloat>

#define HID 240

static inline size_t alignUp(size_t x, size_t a){ return (x + a - 1) / a * a; }

typedef __bf16 bf16x8 __attribute__((ext_vector_type(8)));
typedef unsigned short u16x8 __attribute__((ext_vector_type(8)));
typedef float  f32x16 __attribute__((ext_vector_type(16)));
typedef float  f32x4  __attribute__((ext_vector_type(4)));

__device__ __forceinline__ float b2f(unsigned short u){
    return __uint_as_float(((unsigned)u) << 16);
}
__device__ __forceinline__ unsigned short f2b_rne(float f){
    unsigned r = __float_as_uint(f);
    r += 0x7FFFu + ((r >> 16) & 1u);
    return (unsigned short)(r >> 16);
}

// max of 16 floats as a v_max3 tree (max is exactly associative -> bit-exact)
__device__ __forceinline__ float vmax16(f32x16 a){
    float x0 = fmaxf(fmaxf(a[0],  a[1]),  a[2]);
    float x1 = fmaxf(fmaxf(a[3],  a[4]),  a[5]);
    float x2 = fmaxf(fmaxf(a[6],  a[7]),  a[8]);
    float x3 = fmaxf(fmaxf(a[9],  a[10]), a[11]);
    float x4 = fmaxf(fmaxf(a[12], a[13]), a[14]);
    float y0 = fmaxf(fmaxf(x0, x1), x2);
    float y1 = fmaxf(fmaxf(x3, x4), a[15]);
    return fmaxf(y0, y1);
}

// ---------------- deg_hist (atomic, full grid) + independent prep on extra blocks ----------------
__global__ void k_deg_prep(const int* __restrict__ col, const float* __restrict__ ew,
                           unsigned long long* __restrict__ pk, unsigned* __restrict__ rank,
                           int E, int ne, int N, int nb,
                           const float* __restrict__ x, float* __restrict__ xp,
                           const float* __restrict__ W1, unsigned short* __restrict__ W1f,
                           const float* __restrict__ W2, unsigned short* __restrict__ Bt2h,
                           unsigned short* __restrict__ Bt2l,
                           const float* __restrict__ We, unsigned short* __restrict__ Bt3h,
                           unsigned short* __restrict__ Bt3l){
    int b = blockIdx.x;
    int t = threadIdx.x;
    if (b < ne){
        int e = b * 256 + t;
        if (e < E){
            int c = col[e];
            unsigned q = __float2uint_rn(ew[e] * 1048576.0f);
            unsigned long long old = atomicAdd(&pk[c], (1ull << 40) | (unsigned long long)q);
            rank[e] = (unsigned)(old >> 40);
        }
        return;
    }
    int bb = b - ne;
    if (bb < nb){
        __shared__ float s[1280];
        int rbase = bb * 256;
        #pragma unroll
        for (int c = 0; c < 5; c++){
            int idx = rbase * 5 + t + 256 * c;
            s[t + 256 * c] = (idx < N * 5) ? x[idx] : 0.0f;
        }
        __syncthreads();
        #pragma unroll
        for (int c = 0; c < 8; c++){
            int pos = t + 256 * c;
            int r = pos >> 3, j = pos & 7;
            int grow = rbase + r;
            if (grow < N)
                xp[(size_t)grow * 8 + j] = (j < 5) ? s[r * 5 + j] : 0.0f;
        }
        return;
    }
    bb -= nb;
    if (bb < 32){
        int i = bb * 256 + t;
        if (i < 2 * 8 * 64 * 8){
            int k    = i & 7;
            int lane = (i >> 3) & 63;
            int j    = (i >> 9) & 7;
            int s2   = i >> 12;
            int lm = lane & 31, quad = lane >> 5;
            int kg = quad * 8 + k;
            int colm = 32 * j + lm;
            float v = (kg < 5 && colm < HID) ? W1[kg * HID + colm] : 0.0f;
            unsigned short hi = f2b_rne(v);
            W1f[i] = (s2 == 0) ? hi : f2b_rne(v - b2f(hi));
        }
        return;
    }
    bb -= 32;
    if (bb < 240){
        int i = bb * 256 + t;
        int n = i / HID, k = i - n * HID;
        float v = (n < HID) ? W2[(size_t)k * HID + n] : 0.0f;
        unsigned short hi = f2b_rne(v);
        Bt2h[i] = hi;
        Bt2l[i] = f2b_rne(v - b2f(hi));
        return;
    }
    bb -= 240;
    {
        int i = bb * 256 + t;
        if (i < 128 * HID){
            int n = i / HID, k = i - n * HID;
            float v = (n < 80) ? We[(size_t)k * 80 + n] : 0.0f;
            unsigned short hi = f2b_rne(v);
            Bt3h[i] = hi;
            Bt3l[i] = f2b_rne(v - b2f(hi));
        }
    }
}

// ---------------- unpack pk -> dis,cnt + per-block chunk sums ----------------
__global__ void k_dis_bsum(const unsigned long long* __restrict__ pk,
                           float* __restrict__ dis, unsigned* __restrict__ cnt,
                           unsigned* __restrict__ bsum, int N){
    int b = blockIdx.x;
    int i = b * 256 + threadIdx.x;
    unsigned v = 0u;
    if (i < N){
        unsigned long long p = pk[i];
        unsigned c = (unsigned)(p >> 40);
        cnt[i] = c;
        float deg = 1.0f + (float)(p & 0xFFFFFFFFFFull) * (1.0f / 1048576.0f);
        dis[i] = rsqrtf(deg);
        v = (c + 32u) >> 5;
    }
    #pragma unroll
    for (int o = 32; o > 0; o >>= 1) v += __shfl_down(v, (unsigned)o, 64);
    __shared__ unsigned ws[4];
    int lane = threadIdx.x & 63, w = threadIdx.x >> 6;
    if (lane == 0) ws[w] = v;
    __syncthreads();
    if (threadIdx.x == 0) bsum[b] = ws[0] + ws[1] + ws[2] + ws[3];
}

// ---------------- scan of block sums (nb <= 256); also writes poff[N] ----------------
__global__ void k_bscan(const unsigned* __restrict__ bsum, unsigned* __restrict__ boff,
                        unsigned* __restrict__ poff, int nb, int N){
    __shared__ unsigned s[256];
    int t = threadIdx.x;
    unsigned v = (t < nb) ? bsum[t] : 0u;
    s[t] = v;
    __syncthreads();
    for (int o = 1; o < 256; o <<= 1){
        unsigned u = (t >= o) ? s[t - o] : 0u;
        __syncthreads();
        s[t] += u;
        __syncthreads();
    }
    if (t < nb) boff[t] = s[t] - v;
    if (t == 0) poff[N] = 32u * s[nb - 1];
}

// ---------------- offsets + self-slot/tail fill ----------------
__global__ void k_offs_fill(const unsigned* __restrict__ cnt, const unsigned* __restrict__ boff,
                            const float* __restrict__ dis,
                            unsigned* __restrict__ poff, int2* __restrict__ sedge, int N){
    int b = blockIdx.x, t = threadIdx.x;
    int i = b * 256 + t;
    unsigned c = (i < N) ? cnt[i] : 0u;
    unsigned v = (i < N) ? ((c + 32u) >> 5) : 0u;
    int lane = t & 63, w = t >> 6;
    unsigned x = v;
    #pragma unroll
    for (int o = 1; o < 64; o <<= 1){
        unsigned u = __shfl_up(x, (unsigned)o, 64);
        if (lane >= o) x += u;
    }
    __shared__ unsigned ws[4];
    if (lane == 63) ws[w] = x;
    __syncthreads();
    unsigned wb = 0;
    if (w > 0) wb += ws[0];
    if (w > 1) wb += ws[1];
    if (w > 2) wb += ws[2];
    if (i < N){
        unsigned p = 32u * (boff[b] + wb + x - v);
        poff[i] = p;
        float dd = dis[i];
        int2 sv = make_int2(i, __float_as_int(dd * dd));
        sedge[p] = sv;
        unsigned s1 = p + 32u * v;
        for (unsigned s = p + 1u + c; s < s1; s++) sedge[s] = sv;
    }
}

// ---------------- ATOMIC-FREE scatter: slot = poff[c] + 1 + rank[e] ----------------
__global__ void k_scatter(const int* __restrict__ row, const int* __restrict__ col,
                          const float* __restrict__ ew, const float* __restrict__ dis,
                          const unsigned* __restrict__ poff, const unsigned* __restrict__ rank,
                          int2* __restrict__ sedge, int E){
    int e = blockIdx.x * blockDim.x + threadIdx.x;
    if (e < E){
        int r = row[e], c = col[e];
        float nw = dis[r] * ew[e] * dis[c];
        unsigned p = poff[c] + 1u + rank[e];
        sedge[p] = make_int2(r, __float_as_int(nw));
    }
}

// ---------------- layer-1 fused linear+max-agg via MFMA ----------------
__global__ __launch_bounds__(256) void k_agg1m(const float* __restrict__ xp,
                                               const unsigned short* __restrict__ W1f,
                                               const unsigned* __restrict__ cnt,
                                               const unsigned* __restrict__ poff,
                                               const int2* __restrict__ sedge,
                                               const float* __restrict__ bias,
                                               float* __restrict__ out, int N, int nwaves){
    int wid  = blockIdx.x * 4 + (threadIdx.x >> 6);
    int lane = threadIdx.x & 63;
    int lm   = lane & 31;

    bf16x8 bh[8], bl[8];
    #pragma unroll
    for (int j = 0; j < 8; j++){
        bh[j] = *(const bf16x8*)(W1f + ((size_t)(0 * 8 + j) * 64 + lane) * 8);
        bl[j] = *(const bf16x8*)(W1f + ((size_t)(1 * 8 + j) * 64 + lane) * 8);
    }
    float bv[8];
    #pragma unroll
    for (int j = 0; j < 8; j++){
        int c = 32 * j + lm;
        bv[j] = (c < HID) ? bias[c] : 0.0f;
    }
    const f32x16 zv = {};

    for (int d = wid; d < N; d += nwaves){
        unsigned base = poff[d];
        unsigned nch  = (cnt[d] + 32u) >> 5;
        float m[8];
        #pragma unroll
        for (int j = 0; j < 8; j++) m[j] = -FLT_MAX;

        for (unsigned c = 0; c < nch; c++){
            u16x8 ahu = (u16x8)0, alu = (u16x8)0;
            if (lane < 32){
                int2 e = sedge[base + 32u * c + (unsigned)lm];
                float w = __int_as_float(e.y);
                const float4* xr = (const float4*)(xp + (size_t)e.x * 8);
                float4 x0 = xr[0], x1 = xr[1];
                float p[5] = {w * x0.x, w * x0.y, w * x0.z, w * x0.w, w * x1.x};
                #pragma unroll
                for (int k = 0; k < 5; k++){
                    unsigned short h = f2b_rne(p[k]);
                    ahu[k] = h;
                    alu[k] = f2b_rne(p[k] - b2f(h));
                }
            }
            bf16x8 ah = __builtin_bit_cast(bf16x8, ahu);
            bf16x8 al = __builtin_bit_cast(bf16x8, alu);
            #pragma unroll
            for (int j = 0; j < 8; j += 2){
                f32x16 a0 = __builtin_amdgcn_mfma_f32_32x32x16_bf16(ah, bh[j],     zv, 0, 0, 0);
                f32x16 a1 = __builtin_amdgcn_mfma_f32_32x32x16_bf16(ah, bh[j + 1], zv, 0, 0, 0);
                a0 = __builtin_amdgcn_mfma_f32_32x32x16_bf16(ah, bl[j],     a0, 0, 0, 0);
                a1 = __builtin_amdgcn_mfma_f32_32x32x16_bf16(ah, bl[j + 1], a1, 0, 0, 0);
                a0 = __builtin_amdgcn_mfma_f32_32x32x16_bf16(al, bh[j],     a0, 0, 0, 0);
                a1 = __builtin_amdgcn_mfma_f32_32x32x16_bf16(al, bh[j + 1], a1, 0, 0, 0);
                m[j]     = fmaxf(m[j],     vmax16(a0));
                m[j + 1] = fmaxf(m[j + 1], vmax16(a1));
            }
        }
        float o[8];
        #pragma unroll
        for (int j = 0; j < 8; j++){
            float other = __shfl_xor(m[j], 32, 64);
            o[j] = fmaxf(fmaxf(m[j], other) + bv[j], 0.0f);
        }
        if (lane < 32){
            float* orow = out + (size_t)d * HID;
            #pragma unroll
            for (int j = 0; j < 8; j++){
                int c = 32 * j + lm;
                if (c < HID) orow[c] = o[j];
            }
        }
    }
}

// ---------------- split-bf16 MFMA GEMM, 64-row tiles: C = A(M x 240) @ W(240 x Ncol) ----------------
// OB16: writes chunked layout H2c[n>>5][m][n&31] (Cld = number of rows N) so the
// layer-2 gather reads 64B rows from a 3.2MB per-chunk array (per-XCD L2 resident).
// !OB16: fp32 rows of stride Cld with bias.
template <bool OB16>
__global__ __launch_bounds__(256) void k_gemm_mfma(const float* __restrict__ A,
                                                   const unsigned short* __restrict__ Bth,
                                                   const unsigned short* __restrict__ Btl,
                                                   const float* __restrict__ bias,
                                                   void* __restrict__ Cv,
                                                   int M, int Ncol, int Npad, int Cld){
    __shared__ unsigned short As_hi[64][24];
    __shared__ unsigned short As_lo[64][24];
    const int K = 240;
    int t = threadIdx.x;
    int wave = t >> 6, lane = t & 63;
    int m0 = blockIdx.x * 64;
    int n0 = wave * 64;
    bool wact = n0 < Npad;

    int lm   = lane & 31;
    int quad = lane >> 5;

    f32x16 acc[2][2] = {};   // [m-half][n-tile]

    for (int k0 = 0; k0 < K; k0 += 16){
        {
            int m = t >> 2, kq = (t & 3) * 4;   // 64 rows x 4 cols of float4
            float4 av = make_float4(0.f, 0.f, 0.f, 0.f);
            if (m0 + m < M) av = *(const float4*)(A + (size_t)(m0 + m) * K + k0 + kq);
            ushort4 hi, lo;
            hi.x = f2b_rne(av.x); lo.x = f2b_rne(av.x - b2f(hi.x));
            hi.y = f2b_rne(av.y); lo.y = f2b_rne(av.y - b2f(hi.y));
            hi.z = f2b_rne(av.z); lo.z = f2b_rne(av.z - b2f(hi.z));
            hi.w = f2b_rne(av.w); lo.w = f2b_rne(av.w - b2f(hi.w));
            *(ushort4*)&As_hi[m][kq] = hi;
            *(ushort4*)&As_lo[m][kq] = lo;
        }
        __syncthreads();
        if (wact){
            size_t bo0 = (size_t)(n0 + lm) * K + k0 + quad * 8;
            size_t bo1 = (size_t)(n0 + 32 + lm) * K + k0 + quad * 8;
            bf16x8 bh0 = *(const bf16x8*)(Bth + bo0);
            bf16x8 bl0 = *(const bf16x8*)(Btl + bo0);
            bf16x8 bh1 = *(const bf16x8*)(Bth + bo1);
            bf16x8 bl1 = *(const bf16x8*)(Btl + bo1);
            #pragma unroll
            for (int mh = 0; mh < 2; mh++){
                bf16x8 ah = *(const bf16x8*)&As_hi[32 * mh + lm][quad * 8];
                bf16x8 al = *(const bf16x8*)&As_lo[32 * mh + lm][quad * 8];
                acc[mh][0] = __builtin_amdgcn_mfma_f32_32x32x16_bf16(ah, bh0, acc[mh][0], 0, 0, 0);
                acc[mh][0] = __builtin_amdgcn_mfma_f32_32x32x16_bf16(ah, bl0, acc[mh][0], 0, 0, 0);
                acc[mh][0] = __builtin_amdgcn_mfma_f32_32x32x16_bf16(al, bh0, acc[mh][0], 0, 0, 0);
                acc[mh][1] = __builtin_amdgcn_mfma_f32_32x32x16_bf16(ah, bh1, acc[mh][1], 0, 0, 0);
                acc[mh][1] = __builtin_amdgcn_mfma_f32_32x32x16_bf16(ah, bl1, acc[mh][1], 0, 0, 0);
                acc[mh][1] = __builtin_amdgcn_mfma_f32_32x32x16_bf16(al, bh1, acc[mh][1], 0, 0, 0);
            }
        }
        __syncthreads();
    }

    if (!wact) return;
    #pragma unroll
    for (int mh = 0; mh < 2; mh++){
        #pragma unroll
        for (int h = 0; h < 2; h++){
            int n = n0 + 32 * h + lm;
            if (n >= Ncol) continue;
            float bvv = (!OB16 && bias) ? bias[n] : 0.0f;
            #pragma unroll
            for (int r = 0; r < 16; r++){
                int m = m0 + 32 * mh + (r & 3) + 8 * (r >> 2) + 4 * quad;
                if (m >= M) continue;
                float v = acc[mh][h][r];
                if (OB16){
                    ((unsigned short*)Cv)[(((size_t)(n >> 5) * (size_t)Cld + (size_t)m) << 5) + (n & 31)] = f2b_rne(v);
                } else {
                    ((float*)Cv)[(size_t)m * Cld + n] = v + bvv;
                }
            }
        }
    }
}

// ---------------- layer-2 chunked scatter-max, v2: wave = 8 targets x 1 chunk ----------------
// H2c layout: [chunk][node][32] bf16 (64B rows), chunk = blockIdx&7 -> XCD-pinned (proven:
// FETCH 362->77MB in R3). v2 fixes R3's execution cost: 8 lanes per target (cq=lane&7),
// each lane owns its 4 cols end-to-end (NO cross-lane reduce), exact p0..p1 edge bounds,
// unroll-4 with idempotent clamp. 16x fewer waves, preamble amortized 8x.
// NOTE: chunk 7 covers cols 224..255 but HID=240 -> lanes with c0>=240 must NOT store
// (R4 bug: missing guard corrupted neighbor rows).
__global__ __launch_bounds__(256) void k_aggc2(const unsigned short* __restrict__ H2c,
                                               const unsigned* __restrict__ cnt,
                                               const unsigned* __restrict__ poff,
                                               const int2* __restrict__ sedge,
                                               const float* __restrict__ bias,
                                               float* __restrict__ out, int N){
    int chunk = blockIdx.x & 7;
    int wid   = threadIdx.x >> 6;
    int lane  = threadIdx.x & 63;
    int tg    = lane >> 3;           // target slot within wave (0..7)
    int cq    = lane & 7;            // col quad within chunk (0..7)
    int d     = (blockIdx.x >> 3) * 32 + wid * 8 + tg;
    int c0    = chunk * 32 + cq * 4;
    bool act  = (d < N) && (c0 < HID);

    unsigned p  = (d < N) ? poff[d] : 0u;
    unsigned pe = (d < N && c0 < HID) ? (p + 1u + cnt[d]) : 0u;   // exclusive end

    const unsigned short* base = H2c + (((size_t)chunk * (size_t)N) << 5) + (cq << 2);
    const unsigned long long* se = (const unsigned long long*)sedge;

    float4 m = make_float4(-FLT_MAX, -FLT_MAX, -FLT_MAX, -FLT_MAX);
    while (p < pe){
        unsigned pl = pe - 1u;
        unsigned i1 = (p + 1u < pl) ? p + 1u : pl;
        unsigned i2 = (p + 2u < pl) ? p + 2u : pl;
        unsigned i3 = (p + 3u < pl) ? p + 3u : pl;
        unsigned long long ev0 = __builtin_nontemporal_load(se + p);
        unsigned long long ev1 = __builtin_nontemporal_load(se + i1);
        unsigned long long ev2 = __builtin_nontemporal_load(se + i2);
        unsigned long long ev3 = __builtin_nontemporal_load(se + i3);
        unsigned r0 = (unsigned)ev0; float w0 = __uint_as_float((unsigned)(ev0 >> 32));
        unsigned r1 = (unsigned)ev1; float w1 = __uint_as_float((unsigned)(ev1 >> 32));
        unsigned r2 = (unsigned)ev2; float w2 = __uint_as_float((unsigned)(ev2 >> 32));
        unsigned r3 = (unsigned)ev3; float w3 = __uint_as_float((unsigned)(ev3 >> 32));
        ushort4 g0 = *(const ushort4*)(base + ((size_t)r0 << 5));
        ushort4 g1 = *(const ushort4*)(base + ((size_t)r1 << 5));
        ushort4 g2 = *(const ushort4*)(base + ((size_t)r2 << 5));
        ushort4 g3 = *(const ushort4*)(base + ((size_t)r3 << 5));
        m.x = fmaxf(fmaxf(m.x, w0*b2f(g0.x)), fmaxf(w1*b2f(g1.x), fmaxf(w2*b2f(g2.x), w3*b2f(g3.x))));
        m.y = fmaxf(fmaxf(m.y, w0*b2f(g0.y)), fmaxf(w1*b2f(g1.y), fmaxf(w2*b2f(g2.y), w3*b2f(g3.y))));
        m.z = fmaxf(fmaxf(m.z, w0*b2f(g0.z)), fmaxf(w1*b2f(g1.z), fmaxf(w2*b2f(g2.z), w3*b2f(g3.z))));
        m.w = fmaxf(fmaxf(m.w, w0*b2f(g0.w)), fmaxf(w1*b2f(g1.w), fmaxf(w2*b2f(g2.w), w3*b2f(g3.w))));
        p += 4u;
    }
    if (act){
        float4 b = *(const float4*)(bias + c0);
        f32x4 o4;
        o4[0] = fmaxf(m.x + b.x, 0.0f);
        o4[1] = fmaxf(m.y + b.y, 0.0f);
        o4[2] = fmaxf(m.z + b.z, 0.0f);
        o4[3] = fmaxf(m.w + b.w, 0.0f);
        __builtin_nontemporal_store(o4, (f32x4*)(out + (size_t)d * HID + c0));
    }
}

extern "C" void kernel_launch(void* const* d_in, const int* in_sizes, int n_in,
                              void* d_out, int out_size, void* d_ws, size_t ws_size,
                              hipStream_t stream){
    const float* x  = (const float*)d_in[0];
    const int*   ei = (const int*)  d_in[1];
    const float* ew = (const float*)d_in[2];
    const float* W1 = (const float*)d_in[3];
    const float* b1 = (const float*)d_in[4];
    const float* W2 = (const float*)d_in[5];
    const float* b2 = (const float*)d_in[6];
    const float* We = (const float*)d_in[7];
    const float* be = (const float*)d_in[8];
    float* out = (float*)d_out;

    const int N = in_sizes[0] / 5;
    const int E = in_sizes[2];
    const int* row = ei;
    const int* col = ei + E;
    const int nb = (N + 255) / 256;

    char* w = (char*)d_ws;
    size_t o = 0;
    auto alloc = [&](size_t bytes) -> void* {
        void* p = w + o;
        o = alignUp(o + bytes, 256);
        return p;
    };
    unsigned long long* pk = (unsigned long long*) alloc((size_t)N * 8);
    float*          dis   = (float*)          alloc((size_t)N * 4);
    unsigned*       cnt   = (unsigned*)       alloc((size_t)N * 4);
    unsigned*       poff  = (unsigned*)       alloc((size_t)(N + 1) * 4);
    unsigned*       bsum  = (unsigned*)       alloc((size_t)nb * 4);
    unsigned*       boff  = (unsigned*)       alloc((size_t)nb * 4);
    unsigned*       rank  = (unsigned*)       alloc((size_t)E * 4);
    int2*           sedge = (int2*)           alloc(((size_t)E + 32u * N + 64u) * 8);
    float*          xp    = (float*)          alloc((size_t)N * 8 * 4);
    unsigned short* W1f   = (unsigned short*) alloc((size_t)2 * 8 * 64 * 8 * 2);
    unsigned short* Bt2h  = (unsigned short*) alloc((size_t)256 * HID * 2);
    unsigned short* Bt2l  = (unsigned short*) alloc((size_t)256 * HID * 2);
    unsigned short* Bt3h  = (unsigned short*) alloc((size_t)128 * HID * 2);
    unsigned short* Bt3l  = (unsigned short*) alloc((size_t)128 * HID * 2);
    unsigned short* bufH2 = (unsigned short*) alloc((size_t)8 * N * 32 * 2);   // chunked [8][N][32]
    float*          bufB  = (float*)          alloc((size_t)N * HID * 4);
    (void)ws_size; (void)n_in; (void)out_size;

    int ne = (E + 255) / 256;

    // graph build; independent weight/x prep rides the atomic-bound launch for free
    hipMemsetAsync(pk, 0, (size_t)N * 8, stream);
    k_deg_prep <<<ne + nb + 32 + 240 + 120, 256, 0, stream>>>(col, ew, pk, rank, E, ne, N, nb,
                                                              x, xp, W1, W1f,
                                                              W2, Bt2h, Bt2l,
                                                              We, Bt3h, Bt3l);
    k_dis_bsum <<<nb, 256, 0, stream>>>(pk, dis, cnt, bsum, N);
    k_bscan    <<<1, 256, 0, stream>>>(bsum, boff, poff, nb, N);
    k_offs_fill<<<nb, 256, 0, stream>>>(cnt, boff, dis, poff, sedge, N);
    k_scatter  <<<ne, 256, 0, stream>>>(row, col, ew, dis, poff, rank, sedge, E);

    // layer 1: MFMA fused linear + max-agg + b1 + ReLU
    const int a1blocks = 1536;
    k_agg1m<<<a1blocks, 256, 0, stream>>>(xp, W1f, cnt, poff, sedge, b1, bufB, N, a1blocks * 4);

    // layer 2: split-bf16 MFMA GEMM -> chunked bf16 [8][N][32], then XCD-pinned gather max-agg
    int gm = (N + 63) / 64;
    k_gemm_mfma<true><<<gm, 256, 0, stream>>>(bufB, Bt2h, Bt2l, nullptr, bufH2, N, HID, 256, N);
    k_aggc2<<<8 * ((N + 31) / 32), 256, 0, stream>>>(bufH2, cnt, poff, sedge, b2, bufB, N);

    // readout: split-bf16 MFMA GEMM -> fp32 out + be
    k_gemm_mfma<false><<<gm, 256, 0, stream>>>(bufB, Bt3h, Bt3l, be, out, N, 80, 128, 80);
}

// Round 6
// 556.783 us; speedup vs baseline: 1.1023x; 1.1023x over previous
//
#include <hip/hip_runtime.h>
#include <cfloat>

#define HID 240

static inline size_t alignUp(size_t x, size_t a){ return (x + a - 1) / a * a; }

typedef __bf16 bf16x8 __attribute__((ext_vector_type(8)));
typedef unsigned short u16x8 __attribute__((ext_vector_type(8)));
typedef float  f32x16 __attribute__((ext_vector_type(16)));
typedef float  f32x4  __attribute__((ext_vector_type(4)));
typedef unsigned long long u64x2 __attribute__((ext_vector_type(2)));

__device__ __forceinline__ float b2f(unsigned short u){
    return __uint_as_float(((unsigned)u) << 16);
}
__device__ __forceinline__ unsigned short f2b_rne(float f){
    unsigned r = __float_as_uint(f);
    r += 0x7FFFu + ((r >> 16) & 1u);
    return (unsigned short)(r >> 16);
}

// max of 16 floats as a v_max3 tree (max is exactly associative -> bit-exact)
__device__ __forceinline__ float vmax16(f32x16 a){
    float x0 = fmaxf(fmaxf(a[0],  a[1]),  a[2]);
    float x1 = fmaxf(fmaxf(a[3],  a[4]),  a[5]);
    float x2 = fmaxf(fmaxf(a[6],  a[7]),  a[8]);
    float x3 = fmaxf(fmaxf(a[9],  a[10]), a[11]);
    float x4 = fmaxf(fmaxf(a[12], a[13]), a[14]);
    float y0 = fmaxf(fmaxf(x0, x1), x2);
    float y1 = fmaxf(fmaxf(x3, x4), a[15]);
    return fmaxf(y0, y1);
}

// ---------------- deg_hist (atomic, full grid) + independent prep on extra blocks ----------------
__global__ void k_deg_prep(const int* __restrict__ col, const float* __restrict__ ew,
                           unsigned long long* __restrict__ pk, unsigned* __restrict__ rank,
                           int E, int ne, int N, int nb,
                           const float* __restrict__ x, float* __restrict__ xp,
                           const float* __restrict__ W1, unsigned short* __restrict__ W1f,
                           const float* __restrict__ W2, unsigned short* __restrict__ Bt2h,
                           unsigned short* __restrict__ Bt2l,
                           const float* __restrict__ We, unsigned short* __restrict__ Bt3h,
                           unsigned short* __restrict__ Bt3l){
    int b = blockIdx.x;
    int t = threadIdx.x;
    if (b < ne){
        int e = b * 256 + t;
        if (e < E){
            int c = col[e];
            unsigned q = __float2uint_rn(ew[e] * 1048576.0f);
            unsigned long long old = atomicAdd(&pk[c], (1ull << 40) | (unsigned long long)q);
            rank[e] = (unsigned)(old >> 40);
        }
        return;
    }
    int bb = b - ne;
    if (bb < nb){
        __shared__ float s[1280];
        int rbase = bb * 256;
        #pragma unroll
        for (int c = 0; c < 5; c++){
            int idx = rbase * 5 + t + 256 * c;
            s[t + 256 * c] = (idx < N * 5) ? x[idx] : 0.0f;
        }
        __syncthreads();
        #pragma unroll
        for (int c = 0; c < 8; c++){
            int pos = t + 256 * c;
            int r = pos >> 3, j = pos & 7;
            int grow = rbase + r;
            if (grow < N)
                xp[(size_t)grow * 8 + j] = (j < 5) ? s[r * 5 + j] : 0.0f;
        }
        return;
    }
    bb -= nb;
    if (bb < 32){
        int i = bb * 256 + t;
        if (i < 2 * 8 * 64 * 8){
            int k    = i & 7;
            int lane = (i >> 3) & 63;
            int j    = (i >> 9) & 7;
            int s2   = i >> 12;
            int lm = lane & 31, quad = lane >> 5;
            int kg = quad * 8 + k;
            int colm = 32 * j + lm;
            float v = (kg < 5 && colm < HID) ? W1[kg * HID + colm] : 0.0f;
            unsigned short hi = f2b_rne(v);
            W1f[i] = (s2 == 0) ? hi : f2b_rne(v - b2f(hi));
        }
        return;
    }
    bb -= 32;
    if (bb < 240){
        int i = bb * 256 + t;
        int n = i / HID, k = i - n * HID;
        float v = (n < HID) ? W2[(size_t)k * HID + n] : 0.0f;
        unsigned short hi = f2b_rne(v);
        Bt2h[i] = hi;
        Bt2l[i] = f2b_rne(v - b2f(hi));
        return;
    }
    bb -= 240;
    {
        int i = bb * 256 + t;
        if (i < 128 * HID){
            int n = i / HID, k = i - n * HID;
            float v = (n < 80) ? We[(size_t)k * 80 + n] : 0.0f;
            unsigned short hi = f2b_rne(v);
            Bt3h[i] = hi;
            Bt3l[i] = f2b_rne(v - b2f(hi));
        }
    }
}

// ---------------- unpack pk -> dis,cnt + per-block chunk sums ----------------
__global__ void k_dis_bsum(const unsigned long long* __restrict__ pk,
                           float* __restrict__ dis, unsigned* __restrict__ cnt,
                           unsigned* __restrict__ bsum, int N){
    int b = blockIdx.x;
    int i = b * 256 + threadIdx.x;
    unsigned v = 0u;
    if (i < N){
        unsigned long long p = pk[i];
        unsigned c = (unsigned)(p >> 40);
        cnt[i] = c;
        float deg = 1.0f + (float)(p & 0xFFFFFFFFFFull) * (1.0f / 1048576.0f);
        dis[i] = rsqrtf(deg);
        v = (c + 32u) >> 5;
    }
    #pragma unroll
    for (int o = 32; o > 0; o >>= 1) v += __shfl_down(v, (unsigned)o, 64);
    __shared__ unsigned ws[4];
    int lane = threadIdx.x & 63, w = threadIdx.x >> 6;
    if (lane == 0) ws[w] = v;
    __syncthreads();
    if (threadIdx.x == 0) bsum[b] = ws[0] + ws[1] + ws[2] + ws[3];
}

// ---------------- scan of block sums (nb <= 256); also writes poff[N] ----------------
__global__ void k_bscan(const unsigned* __restrict__ bsum, unsigned* __restrict__ boff,
                        unsigned* __restrict__ poff, int nb, int N){
    __shared__ unsigned s[256];
    int t = threadIdx.x;
    unsigned v = (t < nb) ? bsum[t] : 0u;
    s[t] = v;
    __syncthreads();
    for (int o = 1; o < 256; o <<= 1){
        unsigned u = (t >= o) ? s[t - o] : 0u;
        __syncthreads();
        s[t] += u;
        __syncthreads();
    }
    if (t < nb) boff[t] = s[t] - v;
    if (t == 0) poff[N] = 32u * s[nb - 1];
}

// ---------------- offsets + self-slot/tail fill ----------------
__global__ void k_offs_fill(const unsigned* __restrict__ cnt, const unsigned* __restrict__ boff,
                            const float* __restrict__ dis,
                            unsigned* __restrict__ poff, int2* __restrict__ sedge, int N){
    int b = blockIdx.x, t = threadIdx.x;
    int i = b * 256 + t;
    unsigned c = (i < N) ? cnt[i] : 0u;
    unsigned v = (i < N) ? ((c + 32u) >> 5) : 0u;
    int lane = t & 63, w = t >> 6;
    unsigned x = v;
    #pragma unroll
    for (int o = 1; o < 64; o <<= 1){
        unsigned u = __shfl_up(x, (unsigned)o, 64);
        if (lane >= o) x += u;
    }
    __shared__ unsigned ws[4];
    if (lane == 63) ws[w] = x;
    __syncthreads();
    unsigned wb = 0;
    if (w > 0) wb += ws[0];
    if (w > 1) wb += ws[1];
    if (w > 2) wb += ws[2];
    if (i < N){
        unsigned p = 32u * (boff[b] + wb + x - v);
        poff[i] = p;
        float dd = dis[i];
        int2 sv = make_int2(i, __float_as_int(dd * dd));
        sedge[p] = sv;
        unsigned s1 = p + 32u * v;
        for (unsigned s = p + 1u + c; s < s1; s++) sedge[s] = sv;
    }
}

// ---------------- ATOMIC-FREE scatter: slot = poff[c] + 1 + rank[e] ----------------
__global__ void k_scatter(const int* __restrict__ row, const int* __restrict__ col,
                          const float* __restrict__ ew, const float* __restrict__ dis,
                          const unsigned* __restrict__ poff, const unsigned* __restrict__ rank,
                          int2* __restrict__ sedge, int E){
    int e = blockIdx.x * blockDim.x + threadIdx.x;
    if (e < E){
        int r = row[e], c = col[e];
        float nw = dis[r] * ew[e] * dis[c];
        unsigned p = poff[c] + 1u + rank[e];
        sedge[p] = make_int2(r, __float_as_int(nw));
    }
}

// ---------------- layer-1 fused linear+max-agg via MFMA ----------------
__global__ __launch_bounds__(256) void k_agg1m(const float* __restrict__ xp,
                                               const unsigned short* __restrict__ W1f,
                                               const unsigned* __restrict__ cnt,
                                               const unsigned* __restrict__ poff,
                                               const int2* __restrict__ sedge,
                                               const float* __restrict__ bias,
                                               float* __restrict__ out, int N, int nwaves){
    int wid  = blockIdx.x * 4 + (threadIdx.x >> 6);
    int lane = threadIdx.x & 63;
    int lm   = lane & 31;

    bf16x8 bh[8], bl[8];
    #pragma unroll
    for (int j = 0; j < 8; j++){
        bh[j] = *(const bf16x8*)(W1f + ((size_t)(0 * 8 + j) * 64 + lane) * 8);
        bl[j] = *(const bf16x8*)(W1f + ((size_t)(1 * 8 + j) * 64 + lane) * 8);
    }
    float bv[8];
    #pragma unroll
    for (int j = 0; j < 8; j++){
        int c = 32 * j + lm;
        bv[j] = (c < HID) ? bias[c] : 0.0f;
    }
    const f32x16 zv = {};

    for (int d = wid; d < N; d += nwaves){
        unsigned base = poff[d];
        unsigned nch  = (cnt[d] + 32u) >> 5;
        float m[8];
        #pragma unroll
        for (int j = 0; j < 8; j++) m[j] = -FLT_MAX;

        for (unsigned c = 0; c < nch; c++){
            u16x8 ahu = (u16x8)0, alu = (u16x8)0;
            if (lane < 32){
                int2 e = sedge[base + 32u * c + (unsigned)lm];
                float w = __int_as_float(e.y);
                const float4* xr = (const float4*)(xp + (size_t)e.x * 8);
                float4 x0 = xr[0], x1 = xr[1];
                float p[5] = {w * x0.x, w * x0.y, w * x0.z, w * x0.w, w * x1.x};
                #pragma unroll
                for (int k = 0; k < 5; k++){
                    unsigned short h = f2b_rne(p[k]);
                    ahu[k] = h;
                    alu[k] = f2b_rne(p[k] - b2f(h));
                }
            }
            bf16x8 ah = __builtin_bit_cast(bf16x8, ahu);
            bf16x8 al = __builtin_bit_cast(bf16x8, alu);
            #pragma unroll
            for (int j = 0; j < 8; j += 2){
                f32x16 a0 = __builtin_amdgcn_mfma_f32_32x32x16_bf16(ah, bh[j],     zv, 0, 0, 0);
                f32x16 a1 = __builtin_amdgcn_mfma_f32_32x32x16_bf16(ah, bh[j + 1], zv, 0, 0, 0);
                a0 = __builtin_amdgcn_mfma_f32_32x32x16_bf16(ah, bl[j],     a0, 0, 0, 0);
                a1 = __builtin_amdgcn_mfma_f32_32x32x16_bf16(ah, bl[j + 1], a1, 0, 0, 0);
                a0 = __builtin_amdgcn_mfma_f32_32x32x16_bf16(al, bh[j],     a0, 0, 0, 0);
                a1 = __builtin_amdgcn_mfma_f32_32x32x16_bf16(al, bh[j + 1], a1, 0, 0, 0);
                m[j]     = fmaxf(m[j],     vmax16(a0));
                m[j + 1] = fmaxf(m[j + 1], vmax16(a1));
            }
        }
        float o[8];
        #pragma unroll
        for (int j = 0; j < 8; j++){
            float other = __shfl_xor(m[j], 32, 64);
            o[j] = fmaxf(fmaxf(m[j], other) + bv[j], 0.0f);
        }
        if (lane < 32){
            float* orow = out + (size_t)d * HID;
            #pragma unroll
            for (int j = 0; j < 8; j++){
                int c = 32 * j + lm;
                if (c < HID) orow[c] = o[j];
            }
        }
    }
}

// ---------------- split-bf16 MFMA GEMM, 64-row tiles: C = A(M x 240) @ W(240 x Ncol) ----------------
// OB16: writes chunked layout H2c[n>>5][m][n&31] (Cld = number of rows N) so the
// layer-2 gather reads 64B rows from a 3.2MB per-chunk array (per-XCD L2 resident).
// !OB16: fp32 rows of stride Cld with bias.
template <bool OB16>
__global__ __launch_bounds__(256) void k_gemm_mfma(const float* __restrict__ A,
                                                   const unsigned short* __restrict__ Bth,
                                                   const unsigned short* __restrict__ Btl,
                                                   const float* __restrict__ bias,
                                                   void* __restrict__ Cv,
                                                   int M, int Ncol, int Npad, int Cld){
    __shared__ unsigned short As_hi[64][24];
    __shared__ unsigned short As_lo[64][24];
    const int K = 240;
    int t = threadIdx.x;
    int wave = t >> 6, lane = t & 63;
    int m0 = blockIdx.x * 64;
    int n0 = wave * 64;
    bool wact = n0 < Npad;

    int lm   = lane & 31;
    int quad = lane >> 5;

    f32x16 acc[2][2] = {};   // [m-half][n-tile]

    for (int k0 = 0; k0 < K; k0 += 16){
        {
            int m = t >> 2, kq = (t & 3) * 4;   // 64 rows x 4 cols of float4
            float4 av = make_float4(0.f, 0.f, 0.f, 0.f);
            if (m0 + m < M) av = *(const float4*)(A + (size_t)(m0 + m) * K + k0 + kq);
            ushort4 hi, lo;
            hi.x = f2b_rne(av.x); lo.x = f2b_rne(av.x - b2f(hi.x));
            hi.y = f2b_rne(av.y); lo.y = f2b_rne(av.y - b2f(hi.y));
            hi.z = f2b_rne(av.z); lo.z = f2b_rne(av.z - b2f(hi.z));
            hi.w = f2b_rne(av.w); lo.w = f2b_rne(av.w - b2f(hi.w));
            *(ushort4*)&As_hi[m][kq] = hi;
            *(ushort4*)&As_lo[m][kq] = lo;
        }
        __syncthreads();
        if (wact){
            size_t bo0 = (size_t)(n0 + lm) * K + k0 + quad * 8;
            size_t bo1 = (size_t)(n0 + 32 + lm) * K + k0 + quad * 8;
            bf16x8 bh0 = *(const bf16x8*)(Bth + bo0);
            bf16x8 bl0 = *(const bf16x8*)(Btl + bo0);
            bf16x8 bh1 = *(const bf16x8*)(Bth + bo1);
            bf16x8 bl1 = *(const bf16x8*)(Btl + bo1);
            #pragma unroll
            for (int mh = 0; mh < 2; mh++){
                bf16x8 ah = *(const bf16x8*)&As_hi[32 * mh + lm][quad * 8];
                bf16x8 al = *(const bf16x8*)&As_lo[32 * mh + lm][quad * 8];
                acc[mh][0] = __builtin_amdgcn_mfma_f32_32x32x16_bf16(ah, bh0, acc[mh][0], 0, 0, 0);
                acc[mh][0] = __builtin_amdgcn_mfma_f32_32x32x16_bf16(ah, bl0, acc[mh][0], 0, 0, 0);
                acc[mh][0] = __builtin_amdgcn_mfma_f32_32x32x16_bf16(al, bh0, acc[mh][0], 0, 0, 0);
                acc[mh][1] = __builtin_amdgcn_mfma_f32_32x32x16_bf16(ah, bh1, acc[mh][1], 0, 0, 0);
                acc[mh][1] = __builtin_amdgcn_mfma_f32_32x32x16_bf16(ah, bl1, acc[mh][1], 0, 0, 0);
                acc[mh][1] = __builtin_amdgcn_mfma_f32_32x32x16_bf16(al, bh1, acc[mh][1], 0, 0, 0);
            }
        }
        __syncthreads();
    }

    if (!wact) return;
    #pragma unroll
    for (int mh = 0; mh < 2; mh++){
        #pragma unroll
        for (int h = 0; h < 2; h++){
            int n = n0 + 32 * h + lm;
            if (n >= Ncol) continue;
            float bvv = (!OB16 && bias) ? bias[n] : 0.0f;
            #pragma unroll
            for (int r = 0; r < 16; r++){
                int m = m0 + 32 * mh + (r & 3) + 8 * (r >> 2) + 4 * quad;
                if (m >= M) continue;
                float v = acc[mh][h][r];
                if (OB16){
                    ((unsigned short*)Cv)[(((size_t)(n >> 5) * (size_t)Cld + (size_t)m) << 5) + (n & 31)] = f2b_rne(v);
                } else {
                    ((float*)Cv)[(size_t)m * Cld + n] = v + bvv;
                }
            }
        }
    }
}

// ---------------- layer-2 chunked scatter-max, v3: wave = 8 targets x 1 chunk ----------------
// H2c layout: [chunk][node][32] bf16 (64B rows), chunk = blockIdx&7 -> XCD-pinned (proven:
// FETCH 362->77MB in R3). v3 fixes v2's sedge line-thrash: consume a FULL 64B sedge line
// (8 entries) per iteration via 4x16B loads -- legal because poff is 32-entry aligned and
// the pad region up to the 32-boundary is self-edge-filled (idempotent under max), so
// ng = ceil((cnt+1)/8) groups need no tail clamping. 8 gathers in flight per lane.
// Chunk 7 covers cols 224..255 but HID=240 -> c0>=240 lanes never store.
__global__ __launch_bounds__(256) void k_aggc3(const unsigned short* __restrict__ H2c,
                                               const unsigned* __restrict__ cnt,
                                               const unsigned* __restrict__ poff,
                                               const int2* __restrict__ sedge,
                                               const float* __restrict__ bias,
                                               float* __restrict__ out, int N){
    int chunk = blockIdx.x & 7;
    int wid   = threadIdx.x >> 6;
    int lane  = threadIdx.x & 63;
    int tg    = lane >> 3;           // target slot within wave (0..7)
    int cq    = lane & 7;            // col quad within chunk (0..7)
    int d     = (blockIdx.x >> 3) * 32 + wid * 8 + tg;
    int c0    = chunk * 32 + cq * 4;
    bool act  = (d < N) && (c0 < HID);

    unsigned p  = (d < N) ? poff[d] : 0u;
    unsigned ng = (d < N) ? ((cnt[d] + 8u) >> 3) : 0u;   // ceil((cnt+1)/8), pad is valid

    const unsigned short* base = H2c + (((size_t)chunk * (size_t)N) << 5) + (cq << 2);
    const u64x2* se2 = (const u64x2*)((const unsigned long long*)sedge + p);

    float4 m = make_float4(-FLT_MAX, -FLT_MAX, -FLT_MAX, -FLT_MAX);
    for (unsigned it = 0; it < ng; it++){
        u64x2 ea = __builtin_nontemporal_load(se2 + 0);
        u64x2 eb = __builtin_nontemporal_load(se2 + 1);
        u64x2 ec = __builtin_nontemporal_load(se2 + 2);
        u64x2 ed = __builtin_nontemporal_load(se2 + 3);
        se2 += 4;
        unsigned long long e0 = ea[0], e1 = ea[1], e2 = eb[0], e3 = eb[1];
        unsigned long long e4 = ec[0], e5 = ec[1], e6 = ed[0], e7 = ed[1];
        ushort4 g0 = *(const ushort4*)(base + ((size_t)(unsigned)e0 << 5));
        ushort4 g1 = *(const ushort4*)(base + ((size_t)(unsigned)e1 << 5));
        ushort4 g2 = *(const ushort4*)(base + ((size_t)(unsigned)e2 << 5));
        ushort4 g3 = *(const ushort4*)(base + ((size_t)(unsigned)e3 << 5));
        ushort4 g4 = *(const ushort4*)(base + ((size_t)(unsigned)e4 << 5));
        ushort4 g5 = *(const ushort4*)(base + ((size_t)(unsigned)e5 << 5));
        ushort4 g6 = *(const ushort4*)(base + ((size_t)(unsigned)e6 << 5));
        ushort4 g7 = *(const ushort4*)(base + ((size_t)(unsigned)e7 << 5));
        float w0 = __uint_as_float((unsigned)(e0 >> 32));
        float w1 = __uint_as_float((unsigned)(e1 >> 32));
        float w2 = __uint_as_float((unsigned)(e2 >> 32));
        float w3 = __uint_as_float((unsigned)(e3 >> 32));
        float w4 = __uint_as_float((unsigned)(e4 >> 32));
        float w5 = __uint_as_float((unsigned)(e5 >> 32));
        float w6 = __uint_as_float((unsigned)(e6 >> 32));
        float w7 = __uint_as_float((unsigned)(e7 >> 32));
        // per-component 8-way max tree (encourages v_max3)
        m.x = fmaxf(m.x, fmaxf(fmaxf(fmaxf(w0*b2f(g0.x), w1*b2f(g1.x)), fmaxf(w2*b2f(g2.x), w3*b2f(g3.x))),
                               fmaxf(fmaxf(w4*b2f(g4.x), w5*b2f(g5.x)), fmaxf(w6*b2f(g6.x), w7*b2f(g7.x)))));
        m.y = fmaxf(m.y, fmaxf(fmaxf(fmaxf(w0*b2f(g0.y), w1*b2f(g1.y)), fmaxf(w2*b2f(g2.y), w3*b2f(g3.y))),
                               fmaxf(fmaxf(w4*b2f(g4.y), w5*b2f(g5.y)), fmaxf(w6*b2f(g6.y), w7*b2f(g7.y)))));
        m.z = fmaxf(m.z, fmaxf(fmaxf(fmaxf(w0*b2f(g0.z), w1*b2f(g1.z)), fmaxf(w2*b2f(g2.z), w3*b2f(g3.z))),
                               fmaxf(fmaxf(w4*b2f(g4.z), w5*b2f(g5.z)), fmaxf(w6*b2f(g6.z), w7*b2f(g7.z)))));
        m.w = fmaxf(m.w, fmaxf(fmaxf(fmaxf(w0*b2f(g0.w), w1*b2f(g1.w)), fmaxf(w2*b2f(g2.w), w3*b2f(g3.w))),
                               fmaxf(fmaxf(w4*b2f(g4.w), w5*b2f(g5.w)), fmaxf(w6*b2f(g6.w), w7*b2f(g7.w)))));
    }
    if (act){
        float4 b = *(const float4*)(bias + c0);
        f32x4 o4;
        o4[0] = fmaxf(m.x + b.x, 0.0f);
        o4[1] = fmaxf(m.y + b.y, 0.0f);
        o4[2] = fmaxf(m.z + b.z, 0.0f);
        o4[3] = fmaxf(m.w + b.w, 0.0f);
        __builtin_nontemporal_store(o4, (f32x4*)(out + (size_t)d * HID + c0));
    }
}

extern "C" void kernel_launch(void* const* d_in, const int* in_sizes, int n_in,
                              void* d_out, int out_size, void* d_ws, size_t ws_size,
                              hipStream_t stream){
    const float* x  = (const float*)d_in[0];
    const int*   ei = (const int*)  d_in[1];
    const float* ew = (const float*)d_in[2];
    const float* W1 = (const float*)d_in[3];
    const float* b1 = (const float*)d_in[4];
    const float* W2 = (const float*)d_in[5];
    const float* b2 = (const float*)d_in[6];
    const float* We = (const float*)d_in[7];
    const float* be = (const float*)d_in[8];
    float* out = (float*)d_out;

    const int N = in_sizes[0] / 5;
    const int E = in_sizes[2];
    const int* row = ei;
    const int* col = ei + E;
    const int nb = (N + 255) / 256;

    char* w = (char*)d_ws;
    size_t o = 0;
    auto alloc = [&](size_t bytes) -> void* {
        void* p = w + o;
        o = alignUp(o + bytes, 256);
        return p;
    };
    unsigned long long* pk = (unsigned long long*) alloc((size_t)N * 8);
    float*          dis   = (float*)          alloc((size_t)N * 4);
    unsigned*       cnt   = (unsigned*)       alloc((size_t)N * 4);
    unsigned*       poff  = (unsigned*)       alloc((size_t)(N + 1) * 4);
    unsigned*       bsum  = (unsigned*)       alloc((size_t)nb * 4);
    unsigned*       boff  = (unsigned*)       alloc((size_t)nb * 4);
    unsigned*       rank  = (unsigned*)       alloc((size_t)E * 4);
    int2*           sedge = (int2*)           alloc(((size_t)E + 32u * N + 64u) * 8);
    float*          xp    = (float*)          alloc((size_t)N * 8 * 4);
    unsigned short* W1f   = (unsigned short*) alloc((size_t)2 * 8 * 64 * 8 * 2);
    unsigned short* Bt2h  = (unsigned short*) alloc((size_t)256 * HID * 2);
    unsigned short* Bt2l  = (unsigned short*) alloc((size_t)256 * HID * 2);
    unsigned short* Bt3h  = (unsigned short*) alloc((size_t)128 * HID * 2);
    unsigned short* Bt3l  = (unsigned short*) alloc((size_t)128 * HID * 2);
    unsigned short* bufH2 = (unsigned short*) alloc((size_t)8 * N * 32 * 2);   // chunked [8][N][32]
    float*          bufB  = (float*)          alloc((size_t)N * HID * 4);
    (void)ws_size; (void)n_in; (void)out_size;

    int ne = (E + 255) / 256;

    // graph build; independent weight/x prep rides the atomic-bound launch for free
    hipMemsetAsync(pk, 0, (size_t)N * 8, stream);
    k_deg_prep <<<ne + nb + 32 + 240 + 120, 256, 0, stream>>>(col, ew, pk, rank, E, ne, N, nb,
                                                              x, xp, W1, W1f,
                                                              W2, Bt2h, Bt2l,
                                                              We, Bt3h, Bt3l);
    k_dis_bsum <<<nb, 256, 0, stream>>>(pk, dis, cnt, bsum, N);
    k_bscan    <<<1, 256, 0, stream>>>(bsum, boff, poff, nb, N);
    k_offs_fill<<<nb, 256, 0, stream>>>(cnt, boff, dis, poff, sedge, N);
    k_scatter  <<<ne, 256, 0, stream>>>(row, col, ew, dis, poff, rank, sedge, E);

    // layer 1: MFMA fused linear + max-agg + b1 + ReLU
    const int a1blocks = 1536;
    k_agg1m<<<a1blocks, 256, 0, stream>>>(xp, W1f, cnt, poff, sedge, b1, bufB, N, a1blocks * 4);

    // layer 2: split-bf16 MFMA GEMM -> chunked bf16 [8][N][32], then XCD-pinned gather max-agg
    int gm = (N + 63) / 64;
    k_gemm_mfma<true><<<gm, 256, 0, stream>>>(bufB, Bt2h, Bt2l, nullptr, bufH2, N, HID, 256, N);
    k_aggc3<<<8 * ((N + 31) / 32), 256, 0, stream>>>(bufH2, cnt, poff, sedge, b2, bufB, N);

    // readout: split-bf16 MFMA GEMM -> fp32 out + be
    k_gemm_mfma<false><<<gm, 256, 0, stream>>>(bufB, Bt3h, Bt3l, be, out, N, 80, 128, 80);
}

// Round 7
// 551.216 us; speedup vs baseline: 1.1134x; 1.0101x over previous
//
#include <hip/hip_runtime.h>
#include <cfloat>

#define HID 240

static inline size_t alignUp(size_t x, size_t a){ return (x + a - 1) / a * a; }

typedef __bf16 bf16x8 __attribute__((ext_vector_type(8)));
typedef unsigned short u16x8 __attribute__((ext_vector_type(8)));
typedef float  f32x16 __attribute__((ext_vector_type(16)));
typedef float  f32x4  __attribute__((ext_vector_type(4)));
typedef unsigned long long u64x2 __attribute__((ext_vector_type(2)));

__device__ __forceinline__ float b2f(unsigned short u){
    return __uint_as_float(((unsigned)u) << 16);
}
__device__ __forceinline__ unsigned short f2b_rne(float f){
    unsigned r = __float_as_uint(f);
    r += 0x7FFFu + ((r >> 16) & 1u);
    return (unsigned short)(r >> 16);
}
__device__ __forceinline__ float max3f(float a, float b, float c){
    return fmaxf(fmaxf(a, b), c);   // clang fuses to v_max3_f32
}

// max of 16 floats as a v_max3 tree (max is exactly associative -> bit-exact)
__device__ __forceinline__ float vmax16(f32x16 a){
    float x0 = fmaxf(fmaxf(a[0],  a[1]),  a[2]);
    float x1 = fmaxf(fmaxf(a[3],  a[4]),  a[5]);
    float x2 = fmaxf(fmaxf(a[6],  a[7]),  a[8]);
    float x3 = fmaxf(fmaxf(a[9],  a[10]), a[11]);
    float x4 = fmaxf(fmaxf(a[12], a[13]), a[14]);
    float y0 = fmaxf(fmaxf(x0, x1), x2);
    float y1 = fmaxf(fmaxf(x3, x4), a[15]);
    return fmaxf(y0, y1);
}

// ---------------- deg_hist (atomic, full grid) + independent prep on extra blocks ----------------
__global__ void k_deg_prep(const int* __restrict__ col, const float* __restrict__ ew,
                           unsigned long long* __restrict__ pk, unsigned* __restrict__ rank,
                           int E, int ne, int N, int nb,
                           const float* __restrict__ x, float* __restrict__ xp,
                           const float* __restrict__ W1, unsigned short* __restrict__ W1f,
                           const float* __restrict__ W2, unsigned short* __restrict__ Bt2h,
                           unsigned short* __restrict__ Bt2l,
                           const float* __restrict__ We, unsigned short* __restrict__ Bt3h,
                           unsigned short* __restrict__ Bt3l){
    int b = blockIdx.x;
    int t = threadIdx.x;
    if (b < ne){
        int e = b * 256 + t;
        if (e < E){
            int c = col[e];
            unsigned q = __float2uint_rn(ew[e] * 1048576.0f);
            unsigned long long old = atomicAdd(&pk[c], (1ull << 40) | (unsigned long long)q);
            rank[e] = (unsigned)(old >> 40);
        }
        return;
    }
    int bb = b - ne;
    if (bb < nb){
        __shared__ float s[1280];
        int rbase = bb * 256;
        #pragma unroll
        for (int c = 0; c < 5; c++){
            int idx = rbase * 5 + t + 256 * c;
            s[t + 256 * c] = (idx < N * 5) ? x[idx] : 0.0f;
        }
        __syncthreads();
        #pragma unroll
        for (int c = 0; c < 8; c++){
            int pos = t + 256 * c;
            int r = pos >> 3, j = pos & 7;
            int grow = rbase + r;
            if (grow < N)
                xp[(size_t)grow * 8 + j] = (j < 5) ? s[r * 5 + j] : 0.0f;
        }
        return;
    }
    bb -= nb;
    if (bb < 32){
        int i = bb * 256 + t;
        if (i < 2 * 8 * 64 * 8){
            int k    = i & 7;
            int lane = (i >> 3) & 63;
            int j    = (i >> 9) & 7;
            int s2   = i >> 12;
            int lm = lane & 31, quad = lane >> 5;
            int kg = quad * 8 + k;
            int colm = 32 * j + lm;
            float v = (kg < 5 && colm < HID) ? W1[kg * HID + colm] : 0.0f;
            unsigned short hi = f2b_rne(v);
            W1f[i] = (s2 == 0) ? hi : f2b_rne(v - b2f(hi));
        }
        return;
    }
    bb -= 32;
    if (bb < 240){
        int i = bb * 256 + t;
        int n = i / HID, k = i - n * HID;
        float v = (n < HID) ? W2[(size_t)k * HID + n] : 0.0f;
        unsigned short hi = f2b_rne(v);
        Bt2h[i] = hi;
        Bt2l[i] = f2b_rne(v - b2f(hi));
        return;
    }
    bb -= 240;
    {
        int i = bb * 256 + t;
        if (i < 128 * HID){
            int n = i / HID, k = i - n * HID;
            float v = (n < 80) ? We[(size_t)k * 80 + n] : 0.0f;
            unsigned short hi = f2b_rne(v);
            Bt3h[i] = hi;
            Bt3l[i] = f2b_rne(v - b2f(hi));
        }
    }
}

// ---------------- unpack pk -> dis,cnt + per-block chunk sums ----------------
__global__ void k_dis_bsum(const unsigned long long* __restrict__ pk,
                           float* __restrict__ dis, unsigned* __restrict__ cnt,
                           unsigned* __restrict__ bsum, int N){
    int b = blockIdx.x;
    int i = b * 256 + threadIdx.x;
    unsigned v = 0u;
    if (i < N){
        unsigned long long p = pk[i];
        unsigned c = (unsigned)(p >> 40);
        cnt[i] = c;
        float deg = 1.0f + (float)(p & 0xFFFFFFFFFFull) * (1.0f / 1048576.0f);
        dis[i] = rsqrtf(deg);
        v = (c + 32u) >> 5;
    }
    #pragma unroll
    for (int o = 32; o > 0; o >>= 1) v += __shfl_down(v, (unsigned)o, 64);
    __shared__ unsigned ws[4];
    int lane = threadIdx.x & 63, w = threadIdx.x >> 6;
    if (lane == 0) ws[w] = v;
    __syncthreads();
    if (threadIdx.x == 0) bsum[b] = ws[0] + ws[1] + ws[2] + ws[3];
}

// ---------------- scan of block sums (nb <= 256); also writes poff[N] ----------------
__global__ void k_bscan(const unsigned* __restrict__ bsum, unsigned* __restrict__ boff,
                        unsigned* __restrict__ poff, int nb, int N){
    __shared__ unsigned s[256];
    int t = threadIdx.x;
    unsigned v = (t < nb) ? bsum[t] : 0u;
    s[t] = v;
    __syncthreads();
    for (int o = 1; o < 256; o <<= 1){
        unsigned u = (t >= o) ? s[t - o] : 0u;
        __syncthreads();
        s[t] += u;
        __syncthreads();
    }
    if (t < nb) boff[t] = s[t] - v;
    if (t == 0) poff[N] = 32u * s[nb - 1];
}

// ---------------- offsets + self-slot/tail fill ----------------
__global__ void k_offs_fill(const unsigned* __restrict__ cnt, const unsigned* __restrict__ boff,
                            const float* __restrict__ dis,
                            unsigned* __restrict__ poff, int2* __restrict__ sedge, int N){
    int b = blockIdx.x, t = threadIdx.x;
    int i = b * 256 + t;
    unsigned c = (i < N) ? cnt[i] : 0u;
    unsigned v = (i < N) ? ((c + 32u) >> 5) : 0u;
    int lane = t & 63, w = t >> 6;
    unsigned x = v;
    #pragma unroll
    for (int o = 1; o < 64; o <<= 1){
        unsigned u = __shfl_up(x, (unsigned)o, 64);
        if (lane >= o) x += u;
    }
    __shared__ unsigned ws[4];
    if (lane == 63) ws[w] = x;
    __syncthreads();
    unsigned wb = 0;
    if (w > 0) wb += ws[0];
    if (w > 1) wb += ws[1];
    if (w > 2) wb += ws[2];
    if (i < N){
        unsigned p = 32u * (boff[b] + wb + x - v);
        poff[i] = p;
        float dd = dis[i];
        int2 sv = make_int2(i, __float_as_int(dd * dd));
        sedge[p] = sv;
        unsigned s1 = p + 32u * v;
        for (unsigned s = p + 1u + c; s < s1; s++) sedge[s] = sv;
    }
}

// ---------------- ATOMIC-FREE scatter: slot = poff[c] + 1 + rank[e] ----------------
__global__ void k_scatter(const int* __restrict__ row, const int* __restrict__ col,
                          const float* __restrict__ ew, const float* __restrict__ dis,
                          const unsigned* __restrict__ poff, const unsigned* __restrict__ rank,
                          int2* __restrict__ sedge, int E){
    int e = blockIdx.x * blockDim.x + threadIdx.x;
    if (e < E){
        int r = row[e], c = col[e];
        float nw = dis[r] * ew[e] * dis[c];
        unsigned p = poff[c] + 1u + rank[e];
        sedge[p] = make_int2(r, __float_as_int(nw));
    }
}

// ---------------- layer-1 fused linear+max-agg via MFMA ----------------
__global__ __launch_bounds__(256) void k_agg1m(const float* __restrict__ xp,
                                               const unsigned short* __restrict__ W1f,
                                               const unsigned* __restrict__ cnt,
                                               const unsigned* __restrict__ poff,
                                               const int2* __restrict__ sedge,
                                               const float* __restrict__ bias,
                                               float* __restrict__ out, int N, int nwaves){
    int wid  = blockIdx.x * 4 + (threadIdx.x >> 6);
    int lane = threadIdx.x & 63;
    int lm   = lane & 31;

    bf16x8 bh[8], bl[8];
    #pragma unroll
    for (int j = 0; j < 8; j++){
        bh[j] = *(const bf16x8*)(W1f + ((size_t)(0 * 8 + j) * 64 + lane) * 8);
        bl[j] = *(const bf16x8*)(W1f + ((size_t)(1 * 8 + j) * 64 + lane) * 8);
    }
    float bv[8];
    #pragma unroll
    for (int j = 0; j < 8; j++){
        int c = 32 * j + lm;
        bv[j] = (c < HID) ? bias[c] : 0.0f;
    }
    const f32x16 zv = {};

    for (int d = wid; d < N; d += nwaves){
        unsigned base = poff[d];
        unsigned nch  = (cnt[d] + 32u) >> 5;
        float m[8];
        #pragma unroll
        for (int j = 0; j < 8; j++) m[j] = -FLT_MAX;

        for (unsigned c = 0; c < nch; c++){
            u16x8 ahu = (u16x8)0, alu = (u16x8)0;
            if (lane < 32){
                int2 e = sedge[base + 32u * c + (unsigned)lm];
                float w = __int_as_float(e.y);
                const float4* xr = (const float4*)(xp + (size_t)e.x * 8);
                float4 x0 = xr[0], x1 = xr[1];
                float p[5] = {w * x0.x, w * x0.y, w * x0.z, w * x0.w, w * x1.x};
                #pragma unroll
                for (int k = 0; k < 5; k++){
                    unsigned short h = f2b_rne(p[k]);
                    ahu[k] = h;
                    alu[k] = f2b_rne(p[k] - b2f(h));
                }
            }
            bf16x8 ah = __builtin_bit_cast(bf16x8, ahu);
            bf16x8 al = __builtin_bit_cast(bf16x8, alu);
            #pragma unroll
            for (int j = 0; j < 8; j += 2){
                f32x16 a0 = __builtin_amdgcn_mfma_f32_32x32x16_bf16(ah, bh[j],     zv, 0, 0, 0);
                f32x16 a1 = __builtin_amdgcn_mfma_f32_32x32x16_bf16(ah, bh[j + 1], zv, 0, 0, 0);
                a0 = __builtin_amdgcn_mfma_f32_32x32x16_bf16(ah, bl[j],     a0, 0, 0, 0);
                a1 = __builtin_amdgcn_mfma_f32_32x32x16_bf16(ah, bl[j + 1], a1, 0, 0, 0);
                a0 = __builtin_amdgcn_mfma_f32_32x32x16_bf16(al, bh[j],     a0, 0, 0, 0);
                a1 = __builtin_amdgcn_mfma_f32_32x32x16_bf16(al, bh[j + 1], a1, 0, 0, 0);
                m[j]     = fmaxf(m[j],     vmax16(a0));
                m[j + 1] = fmaxf(m[j + 1], vmax16(a1));
            }
        }
        float o[8];
        #pragma unroll
        for (int j = 0; j < 8; j++){
            float other = __shfl_xor(m[j], 32, 64);
            o[j] = fmaxf(fmaxf(m[j], other) + bv[j], 0.0f);
        }
        if (lane < 32){
            float* orow = out + (size_t)d * HID;
            #pragma unroll
            for (int j = 0; j < 8; j++){
                int c = 32 * j + lm;
                if (c < HID) orow[c] = o[j];
            }
        }
    }
}

// ---------------- split-bf16 MFMA GEMM, 64-row tiles: C = A(M x 240) @ W(240 x Ncol) ----------------
// OB16: writes chunked layout H2c[n>>5][m][n&31] (Cld = number of rows N) so the
// layer-2 gather reads 64B rows from a 3.2MB per-chunk array (per-XCD L2 resident).
// !OB16: fp32 rows of stride Cld with bias.
template <bool OB16>
__global__ __launch_bounds__(256) void k_gemm_mfma(const float* __restrict__ A,
                                                   const unsigned short* __restrict__ Bth,
                                                   const unsigned short* __restrict__ Btl,
                                                   const float* __restrict__ bias,
                                                   void* __restrict__ Cv,
                                                   int M, int Ncol, int Npad, int Cld){
    __shared__ unsigned short As_hi[64][24];
    __shared__ unsigned short As_lo[64][24];
    const int K = 240;
    int t = threadIdx.x;
    int wave = t >> 6, lane = t & 63;
    int m0 = blockIdx.x * 64;
    int n0 = wave * 64;
    bool wact = n0 < Npad;

    int lm   = lane & 31;
    int quad = lane >> 5;

    f32x16 acc[2][2] = {};   // [m-half][n-tile]

    for (int k0 = 0; k0 < K; k0 += 16){
        {
            int m = t >> 2, kq = (t & 3) * 4;   // 64 rows x 4 cols of float4
            float4 av = make_float4(0.f, 0.f, 0.f, 0.f);
            if (m0 + m < M) av = *(const float4*)(A + (size_t)(m0 + m) * K + k0 + kq);
            ushort4 hi, lo;
            hi.x = f2b_rne(av.x); lo.x = f2b_rne(av.x - b2f(hi.x));
            hi.y = f2b_rne(av.y); lo.y = f2b_rne(av.y - b2f(hi.y));
            hi.z = f2b_rne(av.z); lo.z = f2b_rne(av.z - b2f(hi.z));
            hi.w = f2b_rne(av.w); lo.w = f2b_rne(av.w - b2f(hi.w));
            *(ushort4*)&As_hi[m][kq] = hi;
            *(ushort4*)&As_lo[m][kq] = lo;
        }
        __syncthreads();
        if (wact){
            size_t bo0 = (size_t)(n0 + lm) * K + k0 + quad * 8;
            size_t bo1 = (size_t)(n0 + 32 + lm) * K + k0 + quad * 8;
            bf16x8 bh0 = *(const bf16x8*)(Bth + bo0);
            bf16x8 bl0 = *(const bf16x8*)(Btl + bo0);
            bf16x8 bh1 = *(const bf16x8*)(Bth + bo1);
            bf16x8 bl1 = *(const bf16x8*)(Btl + bo1);
            #pragma unroll
            for (int mh = 0; mh < 2; mh++){
                bf16x8 ah = *(const bf16x8*)&As_hi[32 * mh + lm][quad * 8];
                bf16x8 al = *(const bf16x8*)&As_lo[32 * mh + lm][quad * 8];
                acc[mh][0] = __builtin_amdgcn_mfma_f32_32x32x16_bf16(ah, bh0, acc[mh][0], 0, 0, 0);
                acc[mh][0] = __builtin_amdgcn_mfma_f32_32x32x16_bf16(ah, bl0, acc[mh][0], 0, 0, 0);
                acc[mh][0] = __builtin_amdgcn_mfma_f32_32x32x16_bf16(al, bh0, acc[mh][0], 0, 0, 0);
                acc[mh][1] = __builtin_amdgcn_mfma_f32_32x32x16_bf16(ah, bh1, acc[mh][1], 0, 0, 0);
                acc[mh][1] = __builtin_amdgcn_mfma_f32_32x32x16_bf16(ah, bl1, acc[mh][1], 0, 0, 0);
                acc[mh][1] = __builtin_amdgcn_mfma_f32_32x32x16_bf16(al, bh1, acc[mh][1], 0, 0, 0);
            }
        }
        __syncthreads();
    }

    if (!wact) return;
    #pragma unroll
    for (int mh = 0; mh < 2; mh++){
        #pragma unroll
        for (int h = 0; h < 2; h++){
            int n = n0 + 32 * h + lm;
            if (n >= Ncol) continue;
            float bvv = (!OB16 && bias) ? bias[n] : 0.0f;
            #pragma unroll
            for (int r = 0; r < 16; r++){
                int m = m0 + 32 * mh + (r & 3) + 8 * (r >> 2) + 4 * quad;
                if (m >= M) continue;
                float v = acc[mh][h][r];
                if (OB16){
                    ((unsigned short*)Cv)[(((size_t)(n >> 5) * (size_t)Cld + (size_t)m) << 5) + (n & 31)] = f2b_rne(v);
                } else {
                    ((float*)Cv)[(size_t)m * Cld + n] = v + bvv;
                }
            }
        }
    }
}

// ---------------- layer-2 chunked scatter-max, v4: 2-stage sedge prefetch pipeline ----------------
// Same structure as v3 (wave = 8 targets x 1 chunk, full 64B sedge line per iter), plus:
//  - unconditional prefetch of the NEXT sedge line before issuing current gathers, breaking
//    the sedge->gather serial chain (sedge has >=512B valid tail pad; pad = self-edges).
//  - v_max3 reduction trees (bit-exact; halves reduction VALU).
// Chunk 7 covers cols 224..255 but HID=240 -> c0>=240 lanes never store.
__global__ __launch_bounds__(256) void k_aggc4(const unsigned short* __restrict__ H2c,
                                               const unsigned* __restrict__ cnt,
                                               const unsigned* __restrict__ poff,
                                               const int2* __restrict__ sedge,
                                               const float* __restrict__ bias,
                                               float* __restrict__ out, int N){
    int chunk = blockIdx.x & 7;
    int wid   = threadIdx.x >> 6;
    int lane  = threadIdx.x & 63;
    int tg    = lane >> 3;           // target slot within wave (0..7)
    int cq    = lane & 7;            // col quad within chunk (0..7)
    int d     = (blockIdx.x >> 3) * 32 + wid * 8 + tg;
    int c0    = chunk * 32 + cq * 4;
    bool act  = (d < N) && (c0 < HID);

    unsigned p  = (d < N) ? poff[d] : 0u;
    unsigned ng = (d < N) ? ((cnt[d] + 8u) >> 3) : 0u;   // ceil((cnt+1)/8), pad is valid

    const unsigned short* base = H2c + (((size_t)chunk * (size_t)N) << 5) + (cq << 2);
    const u64x2* se2 = (const u64x2*)((const unsigned long long*)sedge + p);

    float4 m = make_float4(-FLT_MAX, -FLT_MAX, -FLT_MAX, -FLT_MAX);

    // stage-0 load (line 0); tail pad guarantees >=64B readable past any group.
    u64x2 ea = __builtin_nontemporal_load(se2 + 0);
    u64x2 eb = __builtin_nontemporal_load(se2 + 1);
    u64x2 ec = __builtin_nontemporal_load(se2 + 2);
    u64x2 ed = __builtin_nontemporal_load(se2 + 3);
    se2 += 4;

    for (unsigned it = 0; it < ng; it++){
        // prefetch next line unconditionally (garbage on last iter, never consumed)
        u64x2 na = __builtin_nontemporal_load(se2 + 0);
        u64x2 nb = __builtin_nontemporal_load(se2 + 1);
        u64x2 nc = __builtin_nontemporal_load(se2 + 2);
        u64x2 nd = __builtin_nontemporal_load(se2 + 3);
        se2 += 4;

        unsigned long long e0 = ea[0], e1 = ea[1], e2 = eb[0], e3 = eb[1];
        unsigned long long e4 = ec[0], e5 = ec[1], e6 = ed[0], e7 = ed[1];
        ushort4 g0 = *(const ushort4*)(base + ((size_t)(unsigned)e0 << 5));
        ushort4 g1 = *(const ushort4*)(base + ((size_t)(unsigned)e1 << 5));
        ushort4 g2 = *(const ushort4*)(base + ((size_t)(unsigned)e2 << 5));
        ushort4 g3 = *(const ushort4*)(base + ((size_t)(unsigned)e3 << 5));
        ushort4 g4 = *(const ushort4*)(base + ((size_t)(unsigned)e4 << 5));
        ushort4 g5 = *(const ushort4*)(base + ((size_t)(unsigned)e5 << 5));
        ushort4 g6 = *(const ushort4*)(base + ((size_t)(unsigned)e6 << 5));
        ushort4 g7 = *(const ushort4*)(base + ((size_t)(unsigned)e7 << 5));
        float w0 = __uint_as_float((unsigned)(e0 >> 32));
        float w1 = __uint_as_float((unsigned)(e1 >> 32));
        float w2 = __uint_as_float((unsigned)(e2 >> 32));
        float w3 = __uint_as_float((unsigned)(e3 >> 32));
        float w4 = __uint_as_float((unsigned)(e4 >> 32));
        float w5 = __uint_as_float((unsigned)(e5 >> 32));
        float w6 = __uint_as_float((unsigned)(e6 >> 32));
        float w7 = __uint_as_float((unsigned)(e7 >> 32));
        // v_max3 trees per component (exactly associative -> bit-exact)
        m.x = max3f(max3f(w0*b2f(g0.x), w1*b2f(g1.x), w2*b2f(g2.x)),
                    max3f(w3*b2f(g3.x), w4*b2f(g4.x), w5*b2f(g5.x)),
                    max3f(w6*b2f(g6.x), w7*b2f(g7.x), m.x));
        m.y = max3f(max3f(w0*b2f(g0.y), w1*b2f(g1.y), w2*b2f(g2.y)),
                    max3f(w3*b2f(g3.y), w4*b2f(g4.y), w5*b2f(g5.y)),
                    max3f(w6*b2f(g6.y), w7*b2f(g7.y), m.y));
        m.z = max3f(max3f(w0*b2f(g0.z), w1*b2f(g1.z), w2*b2f(g2.z)),
                    max3f(w3*b2f(g3.z), w4*b2f(g4.z), w5*b2f(g5.z)),
                    max3f(w6*b2f(g6.z), w7*b2f(g7.z), m.z));
        m.w = max3f(max3f(w0*b2f(g0.w), w1*b2f(g1.w), w2*b2f(g2.w)),
                    max3f(w3*b2f(g3.w), w4*b2f(g4.w), w5*b2f(g5.w)),
                    max3f(w6*b2f(g6.w), w7*b2f(g7.w), m.w));

        ea = na; eb = nb; ec = nc; ed = nd;
    }
    if (act){
        float4 b = *(const float4*)(bias + c0);
        f32x4 o4;
        o4[0] = fmaxf(m.x + b.x, 0.0f);
        o4[1] = fmaxf(m.y + b.y, 0.0f);
        o4[2] = fmaxf(m.z + b.z, 0.0f);
        o4[3] = fmaxf(m.w + b.w, 0.0f);
        __builtin_nontemporal_store(o4, (f32x4*)(out + (size_t)d * HID + c0));
    }
}

extern "C" void kernel_launch(void* const* d_in, const int* in_sizes, int n_in,
                              void* d_out, int out_size, void* d_ws, size_t ws_size,
                              hipStream_t stream){
    const float* x  = (const float*)d_in[0];
    const int*   ei = (const int*)  d_in[1];
    const float* ew = (const float*)d_in[2];
    const float* W1 = (const float*)d_in[3];
    const float* b1 = (const float*)d_in[4];
    const float* W2 = (const float*)d_in[5];
    const float* b2 = (const float*)d_in[6];
    const float* We = (const float*)d_in[7];
    const float* be = (const float*)d_in[8];
    float* out = (float*)d_out;

    const int N = in_sizes[0] / 5;
    const int E = in_sizes[2];
    const int* row = ei;
    const int* col = ei + E;
    const int nb = (N + 255) / 256;

    char* w = (char*)d_ws;
    size_t o = 0;
    auto alloc = [&](size_t bytes) -> void* {
        void* p = w + o;
        o = alignUp(o + bytes, 256);
        return p;
    };
    unsigned long long* pk = (unsigned long long*) alloc((size_t)N * 8);
    float*          dis   = (float*)          alloc((size_t)N * 4);
    unsigned*       cnt   = (unsigned*)       alloc((size_t)N * 4);
    unsigned*       poff  = (unsigned*)       alloc((size_t)(N + 1) * 4);
    unsigned*       bsum  = (unsigned*)       alloc((size_t)nb * 4);
    unsigned*       boff  = (unsigned*)       alloc((size_t)nb * 4);
    unsigned*       rank  = (unsigned*)       alloc((size_t)E * 4);
    int2*           sedge = (int2*)           alloc(((size_t)E + 32u * N + 64u) * 8);
    float*          xp    = (float*)          alloc((size_t)N * 8 * 4);
    unsigned short* W1f   = (unsigned short*) alloc((size_t)2 * 8 * 64 * 8 * 2);
    unsigned short* Bt2h  = (unsigned short*) alloc((size_t)256 * HID * 2);
    unsigned short* Bt2l  = (unsigned short*) alloc((size_t)256 * HID * 2);
    unsigned short* Bt3h  = (unsigned short*) alloc((size_t)128 * HID * 2);
    unsigned short* Bt3l  = (unsigned short*) alloc((size_t)128 * HID * 2);
    unsigned short* bufH2 = (unsigned short*) alloc((size_t)8 * N * 32 * 2);   // chunked [8][N][32]
    float*          bufB  = (float*)          alloc((size_t)N * HID * 4);
    (void)ws_size; (void)n_in; (void)out_size;

    int ne = (E + 255) / 256;

    // graph build; independent weight/x prep rides the atomic-bound launch for free
    hipMemsetAsync(pk, 0, (size_t)N * 8, stream);
    k_deg_prep <<<ne + nb + 32 + 240 + 120, 256, 0, stream>>>(col, ew, pk, rank, E, ne, N, nb,
                                                              x, xp, W1, W1f,
                                                              W2, Bt2h, Bt2l,
                                                              We, Bt3h, Bt3l);
    k_dis_bsum <<<nb, 256, 0, stream>>>(pk, dis, cnt, bsum, N);
    k_bscan    <<<1, 256, 0, stream>>>(bsum, boff, poff, nb, N);
    k_offs_fill<<<nb, 256, 0, stream>>>(cnt, boff, dis, poff, sedge, N);
    k_scatter  <<<ne, 256, 0, stream>>>(row, col, ew, dis, poff, rank, sedge, E);

    // layer 1: MFMA fused linear + max-agg + b1 + ReLU
    const int a1blocks = 1536;
    k_agg1m<<<a1blocks, 256, 0, stream>>>(xp, W1f, cnt, poff, sedge, b1, bufB, N, a1blocks * 4);

    // layer 2: split-bf16 MFMA GEMM -> chunked bf16 [8][N][32], then XCD-pinned gather max-agg
    int gm = (N + 63) / 64;
    k_gemm_mfma<true><<<gm, 256, 0, stream>>>(bufB, Bt2h, Bt2l, nullptr, bufH2, N, HID, 256, N);
    k_aggc4<<<8 * ((N + 31) / 32), 256, 0, stream>>>(bufH2, cnt, poff, sedge, b2, bufB, N);

    // readout: split-bf16 MFMA GEMM -> fp32 out + be
    k_gemm_mfma<false><<<gm, 256, 0, stream>>>(bufB, Bt3h, Bt3l, be, out, N, 80, 128, 80);
}

// Round 8
// 485.257 us; speedup vs baseline: 1.2648x; 1.1359x over previous
//
#include <hip/hip_runtime.h>
#include <cfloat>

#define HID 240

static inline size_t alignUp(size_t x, size_t a){ return (x + a - 1) / a * a; }

typedef __bf16 bf16x8 __attribute__((ext_vector_type(8)));
typedef unsigned short u16x8 __attribute__((ext_vector_type(8)));
typedef float  f32x16 __attribute__((ext_vector_type(16)));
typedef float  f32x4  __attribute__((ext_vector_type(4)));

__device__ __forceinline__ float b2f(unsigned short u){
    return __uint_as_float(((unsigned)u) << 16);
}
__device__ __forceinline__ unsigned short f2b_rne(float f){
    unsigned r = __float_as_uint(f);
    r += 0x7FFFu + ((r >> 16) & 1u);
    return (unsigned short)(r >> 16);
}
__device__ __forceinline__ float max3f(float a, float b, float c){
    return fmaxf(fmaxf(a, b), c);   // clang fuses to v_max3_f32
}

// max of 16 floats as a v_max3 tree (max is exactly associative -> bit-exact)
__device__ __forceinline__ float vmax16(f32x16 a){
    float x0 = fmaxf(fmaxf(a[0],  a[1]),  a[2]);
    float x1 = fmaxf(fmaxf(a[3],  a[4]),  a[5]);
    float x2 = fmaxf(fmaxf(a[6],  a[7]),  a[8]);
    float x3 = fmaxf(fmaxf(a[9],  a[10]), a[11]);
    float x4 = fmaxf(fmaxf(a[12], a[13]), a[14]);
    float y0 = fmaxf(fmaxf(x0, x1), x2);
    float y1 = fmaxf(fmaxf(x3, x4), a[15]);
    return fmaxf(y0, y1);
}

// ---------------- deg_hist (atomic, full grid) + independent prep on extra blocks ----------------
__global__ void k_deg_prep(const int* __restrict__ col, const float* __restrict__ ew,
                           unsigned long long* __restrict__ pk, unsigned* __restrict__ rank,
                           int E, int ne, int N, int nb,
                           const float* __restrict__ x, float* __restrict__ xp,
                           const float* __restrict__ W1, unsigned short* __restrict__ W1f,
                           const float* __restrict__ W2, unsigned short* __restrict__ Bt2h,
                           unsigned short* __restrict__ Bt2l,
                           const float* __restrict__ We, unsigned short* __restrict__ Bt3h,
                           unsigned short* __restrict__ Bt3l){
    int b = blockIdx.x;
    int t = threadIdx.x;
    if (b < ne){
        int e = b * 256 + t;
        if (e < E){
            int c = col[e];
            unsigned q = __float2uint_rn(ew[e] * 1048576.0f);
            unsigned long long old = atomicAdd(&pk[c], (1ull << 40) | (unsigned long long)q);
            rank[e] = (unsigned)(old >> 40);
        }
        return;
    }
    int bb = b - ne;
    if (bb < nb){
        __shared__ float s[1280];
        int rbase = bb * 256;
        #pragma unroll
        for (int c = 0; c < 5; c++){
            int idx = rbase * 5 + t + 256 * c;
            s[t + 256 * c] = (idx < N * 5) ? x[idx] : 0.0f;
        }
        __syncthreads();
        #pragma unroll
        for (int c = 0; c < 8; c++){
            int pos = t + 256 * c;
            int r = pos >> 3, j = pos & 7;
            int grow = rbase + r;
            if (grow < N)
                xp[(size_t)grow * 8 + j] = (j < 5) ? s[r * 5 + j] : 0.0f;
        }
        return;
    }
    bb -= nb;
    if (bb < 32){
        int i = bb * 256 + t;
        if (i < 2 * 8 * 64 * 8){
            int k    = i & 7;
            int lane = (i >> 3) & 63;
            int j    = (i >> 9) & 7;
            int s2   = i >> 12;
            int lm = lane & 31, quad = lane >> 5;
            int kg = quad * 8 + k;
            int colm = 32 * j + lm;
            float v = (kg < 5 && colm < HID) ? W1[kg * HID + colm] : 0.0f;
            unsigned short hi = f2b_rne(v);
            W1f[i] = (s2 == 0) ? hi : f2b_rne(v - b2f(hi));
        }
        return;
    }
    bb -= 32;
    if (bb < 240){
        int i = bb * 256 + t;
        int n = i / HID, k = i - n * HID;
        float v = (n < HID) ? W2[(size_t)k * HID + n] : 0.0f;
        unsigned short hi = f2b_rne(v);
        Bt2h[i] = hi;
        Bt2l[i] = f2b_rne(v - b2f(hi));
        return;
    }
    bb -= 240;
    {
        int i = bb * 256 + t;
        if (i < 128 * HID){
            int n = i / HID, k = i - n * HID;
            float v = (n < 80) ? We[(size_t)k * 80 + n] : 0.0f;
            unsigned short hi = f2b_rne(v);
            Bt3h[i] = hi;
            Bt3l[i] = f2b_rne(v - b2f(hi));
        }
    }
}

// ---------------- unpack pk -> dis,cnt + per-block chunk sums ----------------
__global__ void k_dis_bsum(const unsigned long long* __restrict__ pk,
                           float* __restrict__ dis, unsigned* __restrict__ cnt,
                           unsigned* __restrict__ bsum, int N){
    int b = blockIdx.x;
    int i = b * 256 + threadIdx.x;
    unsigned v = 0u;
    if (i < N){
        unsigned long long p = pk[i];
        unsigned c = (unsigned)(p >> 40);
        cnt[i] = c;
        float deg = 1.0f + (float)(p & 0xFFFFFFFFFFull) * (1.0f / 1048576.0f);
        dis[i] = rsqrtf(deg);
        v = (c + 32u) >> 5;
    }
    #pragma unroll
    for (int o = 32; o > 0; o >>= 1) v += __shfl_down(v, (unsigned)o, 64);
    __shared__ unsigned ws[4];
    int lane = threadIdx.x & 63, w = threadIdx.x >> 6;
    if (lane == 0) ws[w] = v;
    __syncthreads();
    if (threadIdx.x == 0) bsum[b] = ws[0] + ws[1] + ws[2] + ws[3];
}

// ---------------- scan of block sums (nb <= 256); also writes poff[N] ----------------
__global__ void k_bscan(const unsigned* __restrict__ bsum, unsigned* __restrict__ boff,
                        unsigned* __restrict__ poff, int nb, int N){
    __shared__ unsigned s[256];
    int t = threadIdx.x;
    unsigned v = (t < nb) ? bsum[t] : 0u;
    s[t] = v;
    __syncthreads();
    for (int o = 1; o < 256; o <<= 1){
        unsigned u = (t >= o) ? s[t - o] : 0u;
        __syncthreads();
        s[t] += u;
        __syncthreads();
    }
    if (t < nb) boff[t] = s[t] - v;
    if (t == 0) poff[N] = 32u * s[nb - 1];
}

// ---------------- offsets + self-slot/tail fill ----------------
__global__ void k_offs_fill(const unsigned* __restrict__ cnt, const unsigned* __restrict__ boff,
                            const float* __restrict__ dis,
                            unsigned* __restrict__ poff, int2* __restrict__ sedge, int N){
    int b = blockIdx.x, t = threadIdx.x;
    int i = b * 256 + t;
    unsigned c = (i < N) ? cnt[i] : 0u;
    unsigned v = (i < N) ? ((c + 32u) >> 5) : 0u;
    int lane = t & 63, w = t >> 6;
    unsigned x = v;
    #pragma unroll
    for (int o = 1; o < 64; o <<= 1){
        unsigned u = __shfl_up(x, (unsigned)o, 64);
        if (lane >= o) x += u;
    }
    __shared__ unsigned ws[4];
    if (lane == 63) ws[w] = x;
    __syncthreads();
    unsigned wb = 0;
    if (w > 0) wb += ws[0];
    if (w > 1) wb += ws[1];
    if (w > 2) wb += ws[2];
    if (i < N){
        unsigned p = 32u * (boff[b] + wb + x - v);
        poff[i] = p;
        float dd = dis[i];
        int2 sv = make_int2(i, __float_as_int(dd * dd));
        sedge[p] = sv;
        unsigned s1 = p + 32u * v;
        for (unsigned s = p + 1u + c; s < s1; s++) sedge[s] = sv;
    }
}

// ---------------- ATOMIC-FREE scatter: slot = poff[c] + 1 + rank[e] ----------------
__global__ void k_scatter(const int* __restrict__ row, const int* __restrict__ col,
                          const float* __restrict__ ew, const float* __restrict__ dis,
                          const unsigned* __restrict__ poff, const unsigned* __restrict__ rank,
                          int2* __restrict__ sedge, int E){
    int e = blockIdx.x * blockDim.x + threadIdx.x;
    if (e < E){
        int r = row[e], c = col[e];
        float nw = dis[r] * ew[e] * dis[c];
        unsigned p = poff[c] + 1u + rank[e];
        sedge[p] = make_int2(r, __float_as_int(nw));
    }
}

// ---------------- layer-1 fused linear+max-agg via MFMA ----------------
__global__ __launch_bounds__(256) void k_agg1m(const float* __restrict__ xp,
                                               const unsigned short* __restrict__ W1f,
                                               const unsigned* __restrict__ cnt,
                                               const unsigned* __restrict__ poff,
                                               const int2* __restrict__ sedge,
                                               const float* __restrict__ bias,
                                               float* __restrict__ out, int N, int nwaves){
    int wid  = blockIdx.x * 4 + (threadIdx.x >> 6);
    int lane = threadIdx.x & 63;
    int lm   = lane & 31;

    bf16x8 bh[8], bl[8];
    #pragma unroll
    for (int j = 0; j < 8; j++){
        bh[j] = *(const bf16x8*)(W1f + ((size_t)(0 * 8 + j) * 64 + lane) * 8);
        bl[j] = *(const bf16x8*)(W1f + ((size_t)(1 * 8 + j) * 64 + lane) * 8);
    }
    float bv[8];
    #pragma unroll
    for (int j = 0; j < 8; j++){
        int c = 32 * j + lm;
        bv[j] = (c < HID) ? bias[c] : 0.0f;
    }
    const f32x16 zv = {};

    for (int d = wid; d < N; d += nwaves){
        unsigned base = poff[d];
        unsigned nch  = (cnt[d] + 32u) >> 5;
        float m[8];
        #pragma unroll
        for (int j = 0; j < 8; j++) m[j] = -FLT_MAX;

        for (unsigned c = 0; c < nch; c++){
            u16x8 ahu = (u16x8)0, alu = (u16x8)0;
            if (lane < 32){
                int2 e = sedge[base + 32u * c + (unsigned)lm];
                float w = __int_as_float(e.y);
                const float4* xr = (const float4*)(xp + (size_t)e.x * 8);
                float4 x0 = xr[0], x1 = xr[1];
                float p[5] = {w * x0.x, w * x0.y, w * x0.z, w * x0.w, w * x1.x};
                #pragma unroll
                for (int k = 0; k < 5; k++){
                    unsigned short h = f2b_rne(p[k]);
                    ahu[k] = h;
                    alu[k] = f2b_rne(p[k] - b2f(h));
                }
            }
            bf16x8 ah = __builtin_bit_cast(bf16x8, ahu);
            bf16x8 al = __builtin_bit_cast(bf16x8, alu);
            #pragma unroll
            for (int j = 0; j < 8; j += 2){
                f32x16 a0 = __builtin_amdgcn_mfma_f32_32x32x16_bf16(ah, bh[j],     zv, 0, 0, 0);
                f32x16 a1 = __builtin_amdgcn_mfma_f32_32x32x16_bf16(ah, bh[j + 1], zv, 0, 0, 0);
                a0 = __builtin_amdgcn_mfma_f32_32x32x16_bf16(ah, bl[j],     a0, 0, 0, 0);
                a1 = __builtin_amdgcn_mfma_f32_32x32x16_bf16(ah, bl[j + 1], a1, 0, 0, 0);
                a0 = __builtin_amdgcn_mfma_f32_32x32x16_bf16(al, bh[j],     a0, 0, 0, 0);
                a1 = __builtin_amdgcn_mfma_f32_32x32x16_bf16(al, bh[j + 1], a1, 0, 0, 0);
                m[j]     = fmaxf(m[j],     vmax16(a0));
                m[j + 1] = fmaxf(m[j + 1], vmax16(a1));
            }
        }
        float o[8];
        #pragma unroll
        for (int j = 0; j < 8; j++){
            float other = __shfl_xor(m[j], 32, 64);
            o[j] = fmaxf(fmaxf(m[j], other) + bv[j], 0.0f);
        }
        if (lane < 32){
            float* orow = out + (size_t)d * HID;
            #pragma unroll
            for (int j = 0; j < 8; j++){
                int c = 32 * j + lm;
                if (c < HID) orow[c] = o[j];
            }
        }
    }
}

// ---------------- split-bf16 MFMA GEMM, 64-row tiles: C = A(M x 240) @ W(240 x Ncol) ----------------
// OB16: bf16 rows at stride Cld (=256 -> 512B line-aligned rows for the gather).
// !OB16: fp32 rows of stride Cld with bias.
template <bool OB16>
__global__ __launch_bounds__(256) void k_gemm_mfma(const float* __restrict__ A,
                                                   const unsigned short* __restrict__ Bth,
                                                   const unsigned short* __restrict__ Btl,
                                                   const float* __restrict__ bias,
                                                   void* __restrict__ Cv,
                                                   int M, int Ncol, int Npad, int Cld){
    __shared__ unsigned short As_hi[64][24];
    __shared__ unsigned short As_lo[64][24];
    const int K = 240;
    int t = threadIdx.x;
    int wave = t >> 6, lane = t & 63;
    int m0 = blockIdx.x * 64;
    int n0 = wave * 64;
    bool wact = n0 < Npad;

    int lm   = lane & 31;
    int quad = lane >> 5;

    f32x16 acc[2][2] = {};   // [m-half][n-tile]

    for (int k0 = 0; k0 < K; k0 += 16){
        {
            int m = t >> 2, kq = (t & 3) * 4;   // 64 rows x 4 cols of float4
            float4 av = make_float4(0.f, 0.f, 0.f, 0.f);
            if (m0 + m < M) av = *(const float4*)(A + (size_t)(m0 + m) * K + k0 + kq);
            ushort4 hi, lo;
            hi.x = f2b_rne(av.x); lo.x = f2b_rne(av.x - b2f(hi.x));
            hi.y = f2b_rne(av.y); lo.y = f2b_rne(av.y - b2f(hi.y));
            hi.z = f2b_rne(av.z); lo.z = f2b_rne(av.z - b2f(hi.z));
            hi.w = f2b_rne(av.w); lo.w = f2b_rne(av.w - b2f(hi.w));
            *(ushort4*)&As_hi[m][kq] = hi;
            *(ushort4*)&As_lo[m][kq] = lo;
        }
        __syncthreads();
        if (wact){
            size_t bo0 = (size_t)(n0 + lm) * K + k0 + quad * 8;
            size_t bo1 = (size_t)(n0 + 32 + lm) * K + k0 + quad * 8;
            bf16x8 bh0 = *(const bf16x8*)(Bth + bo0);
            bf16x8 bl0 = *(const bf16x8*)(Btl + bo0);
            bf16x8 bh1 = *(const bf16x8*)(Bth + bo1);
            bf16x8 bl1 = *(const bf16x8*)(Btl + bo1);
            #pragma unroll
            for (int mh = 0; mh < 2; mh++){
                bf16x8 ah = *(const bf16x8*)&As_hi[32 * mh + lm][quad * 8];
                bf16x8 al = *(const bf16x8*)&As_lo[32 * mh + lm][quad * 8];
                acc[mh][0] = __builtin_amdgcn_mfma_f32_32x32x16_bf16(ah, bh0, acc[mh][0], 0, 0, 0);
                acc[mh][0] = __builtin_amdgcn_mfma_f32_32x32x16_bf16(ah, bl0, acc[mh][0], 0, 0, 0);
                acc[mh][0] = __builtin_amdgcn_mfma_f32_32x32x16_bf16(al, bh0, acc[mh][0], 0, 0, 0);
                acc[mh][1] = __builtin_amdgcn_mfma_f32_32x32x16_bf16(ah, bh1, acc[mh][1], 0, 0, 0);
                acc[mh][1] = __builtin_amdgcn_mfma_f32_32x32x16_bf16(ah, bl1, acc[mh][1], 0, 0, 0);
                acc[mh][1] = __builtin_amdgcn_mfma_f32_32x32x16_bf16(al, bh1, acc[mh][1], 0, 0, 0);
            }
        }
        __syncthreads();
    }

    if (!wact) return;
    #pragma unroll
    for (int mh = 0; mh < 2; mh++){
        #pragma unroll
        for (int h = 0; h < 2; h++){
            int n = n0 + 32 * h + lm;
            if (n >= Ncol) continue;
            float bvv = (!OB16 && bias) ? bias[n] : 0.0f;
            #pragma unroll
            for (int r = 0; r < 16; r++){
                int m = m0 + 32 * mh + (r & 3) + 8 * (r >> 2) + 4 * quad;
                if (m >= M) continue;
                float v = acc[mh][h][r];
                if (OB16){
                    ((unsigned short*)Cv)[(size_t)m * Cld + n] = f2b_rne(v);
                } else {
                    ((float*)Cv)[(size_t)m * Cld + n] = v + bvv;
                }
            }
        }
    }
}

// ---------------- layer-2 scatter-max over bf16 rows (512B-aligned), +bias, ReLU ----------------
// R1 structure (best measured: 116us) + unroll-8 via padded bounds: the sedge region is
// self-edge-filled up to the 32-aligned boundary, so ng8 = ceil((cnt+1)/8) groups of 8
// are ALL valid (pad re-reads are idempotent under max) -> no tail logic, 8 gathers in flight.
__global__ __launch_bounds__(256) void k_aggb(const unsigned short* __restrict__ H2,
                                              const unsigned* __restrict__ cnt,
                                              const unsigned* __restrict__ poff,
                                              const int2* __restrict__ sedge,
                                              const float* __restrict__ bias,
                                              float* __restrict__ out, int N){
    int d    = blockIdx.x * 4 + (threadIdx.x >> 6);
    int lane = threadIdx.x & 63;
    if (d >= N) return;
    bool act = lane < 60;

    unsigned p0  = poff[d];
    unsigned ng8 = (cnt[d] + 8u) >> 3;   // ceil((cnt+1)/8); pad slots are self-edges (valid)
    const int2* se = sedge + p0;

    float4 m = make_float4(-FLT_MAX, -FLT_MAX, -FLT_MAX, -FLT_MAX);
    for (unsigned it = 0; it < ng8; it++){
        int2 e0 = se[0], e1 = se[1], e2 = se[2], e3 = se[3];
        int2 e4 = se[4], e5 = se[5], e6 = se[6], e7 = se[7];
        se += 8;
        if (act){
            ushort4 g0 = ((const ushort4*)(H2 + ((size_t)(unsigned)e0.x << 8)))[lane];
            ushort4 g1 = ((const ushort4*)(H2 + ((size_t)(unsigned)e1.x << 8)))[lane];
            ushort4 g2 = ((const ushort4*)(H2 + ((size_t)(unsigned)e2.x << 8)))[lane];
            ushort4 g3 = ((const ushort4*)(H2 + ((size_t)(unsigned)e3.x << 8)))[lane];
            ushort4 g4 = ((const ushort4*)(H2 + ((size_t)(unsigned)e4.x << 8)))[lane];
            ushort4 g5 = ((const ushort4*)(H2 + ((size_t)(unsigned)e5.x << 8)))[lane];
            ushort4 g6 = ((const ushort4*)(H2 + ((size_t)(unsigned)e6.x << 8)))[lane];
            ushort4 g7 = ((const ushort4*)(H2 + ((size_t)(unsigned)e7.x << 8)))[lane];
            float w0 = __int_as_float(e0.y), w1 = __int_as_float(e1.y);
            float w2 = __int_as_float(e2.y), w3 = __int_as_float(e3.y);
            float w4 = __int_as_float(e4.y), w5 = __int_as_float(e5.y);
            float w6 = __int_as_float(e6.y), w7 = __int_as_float(e7.y);
            m.x = max3f(max3f(w0*b2f(g0.x), w1*b2f(g1.x), w2*b2f(g2.x)),
                        max3f(w3*b2f(g3.x), w4*b2f(g4.x), w5*b2f(g5.x)),
                        max3f(w6*b2f(g6.x), w7*b2f(g7.x), m.x));
            m.y = max3f(max3f(w0*b2f(g0.y), w1*b2f(g1.y), w2*b2f(g2.y)),
                        max3f(w3*b2f(g3.y), w4*b2f(g4.y), w5*b2f(g5.y)),
                        max3f(w6*b2f(g6.y), w7*b2f(g7.y), m.y));
            m.z = max3f(max3f(w0*b2f(g0.z), w1*b2f(g1.z), w2*b2f(g2.z)),
                        max3f(w3*b2f(g3.z), w4*b2f(g4.z), w5*b2f(g5.z)),
                        max3f(w6*b2f(g6.z), w7*b2f(g7.z), m.z));
            m.w = max3f(max3f(w0*b2f(g0.w), w1*b2f(g1.w), w2*b2f(g2.w)),
                        max3f(w3*b2f(g3.w), w4*b2f(g4.w), w5*b2f(g5.w)),
                        max3f(w6*b2f(g6.w), w7*b2f(g7.w), m.w));
        }
    }
    if (act){
        float4 b = ((const float4*)bias)[lane];
        float4 o;
        o.x = fmaxf(m.x + b.x, 0.0f);
        o.y = fmaxf(m.y + b.y, 0.0f);
        o.z = fmaxf(m.z + b.z, 0.0f);
        o.w = fmaxf(m.w + b.w, 0.0f);
        ((float4*)(out + (size_t)d * HID))[lane] = o;
    }
}

extern "C" void kernel_launch(void* const* d_in, const int* in_sizes, int n_in,
                              void* d_out, int out_size, void* d_ws, size_t ws_size,
                              hipStream_t stream){
    const float* x  = (const float*)d_in[0];
    const int*   ei = (const int*)  d_in[1];
    const float* ew = (const float*)d_in[2];
    const float* W1 = (const float*)d_in[3];
    const float* b1 = (const float*)d_in[4];
    const float* W2 = (const float*)d_in[5];
    const float* b2 = (const float*)d_in[6];
    const float* We = (const float*)d_in[7];
    const float* be = (const float*)d_in[8];
    float* out = (float*)d_out;

    const int N = in_sizes[0] / 5;
    const int E = in_sizes[2];
    const int* row = ei;
    const int* col = ei + E;
    const int nb = (N + 255) / 256;

    char* w = (char*)d_ws;
    size_t o = 0;
    auto alloc = [&](size_t bytes) -> void* {
        void* p = w + o;
        o = alignUp(o + bytes, 256);
        return p;
    };
    unsigned long long* pk = (unsigned long long*) alloc((size_t)N * 8);
    float*          dis   = (float*)          alloc((size_t)N * 4);
    unsigned*       cnt   = (unsigned*)       alloc((size_t)N * 4);
    unsigned*       poff  = (unsigned*)       alloc((size_t)(N + 1) * 4);
    unsigned*       bsum  = (unsigned*)       alloc((size_t)nb * 4);
    unsigned*       boff  = (unsigned*)       alloc((size_t)nb * 4);
    unsigned*       rank  = (unsigned*)       alloc((size_t)E * 4);
    int2*           sedge = (int2*)           alloc(((size_t)E + 32u * N + 64u) * 8);
    float*          xp    = (float*)          alloc((size_t)N * 8 * 4);
    unsigned short* W1f   = (unsigned short*) alloc((size_t)2 * 8 * 64 * 8 * 2);
    unsigned short* Bt2h  = (unsigned short*) alloc((size_t)256 * HID * 2);
    unsigned short* Bt2l  = (unsigned short*) alloc((size_t)256 * HID * 2);
    unsigned short* Bt3h  = (unsigned short*) alloc((size_t)128 * HID * 2);
    unsigned short* Bt3l  = (unsigned short*) alloc((size_t)128 * HID * 2);
    unsigned short* bufH2 = (unsigned short*) alloc((size_t)N * 256 * 2);   // 512B-aligned rows
    float*          bufB  = (float*)          alloc((size_t)N * HID * 4);
    (void)ws_size; (void)n_in; (void)out_size;

    int ne = (E + 255) / 256;

    // graph build; independent weight/x prep rides the atomic-bound launch for free
    hipMemsetAsync(pk, 0, (size_t)N * 8, stream);
    k_deg_prep <<<ne + nb + 32 + 240 + 120, 256, 0, stream>>>(col, ew, pk, rank, E, ne, N, nb,
                                                              x, xp, W1, W1f,
                                                              W2, Bt2h, Bt2l,
                                                              We, Bt3h, Bt3l);
    k_dis_bsum <<<nb, 256, 0, stream>>>(pk, dis, cnt, bsum, N);
    k_bscan    <<<1, 256, 0, stream>>>(bsum, boff, poff, nb, N);
    k_offs_fill<<<nb, 256, 0, stream>>>(cnt, boff, dis, poff, sedge, N);
    k_scatter  <<<ne, 256, 0, stream>>>(row, col, ew, dis, poff, rank, sedge, E);

    // layer 1: MFMA fused linear + max-agg + b1 + ReLU
    const int a1blocks = 1536;
    k_agg1m<<<a1blocks, 256, 0, stream>>>(xp, W1f, cnt, poff, sedge, b1, bufB, N, a1blocks * 4);

    // layer 2: split-bf16 MFMA GEMM (64-row tiles) -> bf16 rows (stride 256), then gather max-agg
    int gm = (N + 63) / 64;
    k_gemm_mfma<true><<<gm, 256, 0, stream>>>(bufB, Bt2h, Bt2l, nullptr, bufH2, N, HID, 256, 256);
    k_aggb<<<(N + 3) / 4, 256, 0, stream>>>(bufH2, cnt, poff, sedge, b2, bufB, N);

    // readout: split-bf16 MFMA GEMM -> fp32 out + be
    k_gemm_mfma<false><<<gm, 256, 0, stream>>>(bufB, Bt3h, Bt3l, be, out, N, 80, 128, 80);
}

// Round 9
// 452.030 us; speedup vs baseline: 1.3577x; 1.0735x over previous
//
#include <hip/hip_runtime.h>
#include <cfloat>

#define HID 240

static inline size_t alignUp(size_t x, size_t a){ return (x + a - 1) / a * a; }

typedef __bf16 bf16x8 __attribute__((ext_vector_type(8)));
typedef unsigned short u16x8 __attribute__((ext_vector_type(8)));
typedef float  f32x16 __attribute__((ext_vector_type(16)));
typedef float  f32x4  __attribute__((ext_vector_type(4)));

__device__ __forceinline__ float b2f(unsigned short u){
    return __uint_as_float(((unsigned)u) << 16);
}
__device__ __forceinline__ unsigned short f2b_rne(float f){
    unsigned r = __float_as_uint(f);
    r += 0x7FFFu + ((r >> 16) & 1u);
    return (unsigned short)(r >> 16);
}
__device__ __forceinline__ float max3f(float a, float b, float c){
    return fmaxf(fmaxf(a, b), c);   // clang fuses to v_max3_f32
}

// max of 16 floats as a v_max3 tree (max is exactly associative -> bit-exact)
__device__ __forceinline__ float vmax16(f32x16 a){
    float x0 = fmaxf(fmaxf(a[0],  a[1]),  a[2]);
    float x1 = fmaxf(fmaxf(a[3],  a[4]),  a[5]);
    float x2 = fmaxf(fmaxf(a[6],  a[7]),  a[8]);
    float x3 = fmaxf(fmaxf(a[9],  a[10]), a[11]);
    float x4 = fmaxf(fmaxf(a[12], a[13]), a[14]);
    float y0 = fmaxf(fmaxf(x0, x1), x2);
    float y1 = fmaxf(fmaxf(x3, x4), a[15]);
    return fmaxf(y0, y1);
}

// ---------------- deg_hist (atomic, full grid) + independent prep on extra blocks ----------------
__global__ void k_deg_prep(const int* __restrict__ col, const float* __restrict__ ew,
                           unsigned long long* __restrict__ pk, unsigned* __restrict__ rank,
                           int E, int ne, int N, int nb,
                           const float* __restrict__ x, float* __restrict__ xp,
                           const float* __restrict__ W1, unsigned short* __restrict__ W1f,
                           const float* __restrict__ W2, unsigned short* __restrict__ Bt2h,
                           unsigned short* __restrict__ Bt2l,
                           const float* __restrict__ We, unsigned short* __restrict__ Bt3h,
                           unsigned short* __restrict__ Bt3l){
    int b = blockIdx.x;
    int t = threadIdx.x;
    if (b < ne){
        int e = b * 256 + t;
        if (e < E){
            int c = col[e];
            unsigned q = __float2uint_rn(ew[e] * 1048576.0f);
            unsigned long long old = atomicAdd(&pk[c], (1ull << 40) | (unsigned long long)q);
            rank[e] = (unsigned)(old >> 40);
        }
        return;
    }
    int bb = b - ne;
    if (bb < nb){
        __shared__ float s[1280];
        int rbase = bb * 256;
        #pragma unroll
        for (int c = 0; c < 5; c++){
            int idx = rbase * 5 + t + 256 * c;
            s[t + 256 * c] = (idx < N * 5) ? x[idx] : 0.0f;
        }
        __syncthreads();
        #pragma unroll
        for (int c = 0; c < 8; c++){
            int pos = t + 256 * c;
            int r = pos >> 3, j = pos & 7;
            int grow = rbase + r;
            if (grow < N)
                xp[(size_t)grow * 8 + j] = (j < 5) ? s[r * 5 + j] : 0.0f;
        }
        return;
    }
    bb -= nb;
    if (bb < 32){
        int i = bb * 256 + t;
        if (i < 2 * 8 * 64 * 8){
            int k    = i & 7;
            int lane = (i >> 3) & 63;
            int j    = (i >> 9) & 7;
            int s2   = i >> 12;
            int lm = lane & 31, quad = lane >> 5;
            int kg = quad * 8 + k;
            int colm = 32 * j + lm;
            float v = (kg < 5 && colm < HID) ? W1[kg * HID + colm] : 0.0f;
            unsigned short hi = f2b_rne(v);
            W1f[i] = (s2 == 0) ? hi : f2b_rne(v - b2f(hi));
        }
        return;
    }
    bb -= 32;
    if (bb < 240){
        int i = bb * 256 + t;
        int n = i / HID, k = i - n * HID;
        float v = (n < HID) ? W2[(size_t)k * HID + n] : 0.0f;
        unsigned short hi = f2b_rne(v);
        Bt2h[i] = hi;
        Bt2l[i] = f2b_rne(v - b2f(hi));
        return;
    }
    bb -= 240;
    {
        int i = bb * 256 + t;
        if (i < 128 * HID){
            int n = i / HID, k = i - n * HID;
            float v = (n < 80) ? We[(size_t)k * 80 + n] : 0.0f;
            unsigned short hi = f2b_rne(v);
            Bt3h[i] = hi;
            Bt3l[i] = f2b_rne(v - b2f(hi));
        }
    }
}

// ---------------- unpack pk -> dis,cnt + per-block chunk sums ----------------
__global__ void k_dis_bsum(const unsigned long long* __restrict__ pk,
                           float* __restrict__ dis, unsigned* __restrict__ cnt,
                           unsigned* __restrict__ bsum, int N){
    int b = blockIdx.x;
    int i = b * 256 + threadIdx.x;
    unsigned v = 0u;
    if (i < N){
        unsigned long long p = pk[i];
        unsigned c = (unsigned)(p >> 40);
        cnt[i] = c;
        float deg = 1.0f + (float)(p & 0xFFFFFFFFFFull) * (1.0f / 1048576.0f);
        dis[i] = rsqrtf(deg);
        v = (c + 32u) >> 5;
    }
    #pragma unroll
    for (int o = 32; o > 0; o >>= 1) v += __shfl_down(v, (unsigned)o, 64);
    __shared__ unsigned ws[4];
    int lane = threadIdx.x & 63, w = threadIdx.x >> 6;
    if (lane == 0) ws[w] = v;
    __syncthreads();
    if (threadIdx.x == 0) bsum[b] = ws[0] + ws[1] + ws[2] + ws[3];
}

// ---------------- scan of block sums (nb <= 256); also writes poff[N] ----------------
__global__ void k_bscan(const unsigned* __restrict__ bsum, unsigned* __restrict__ boff,
                        unsigned* __restrict__ poff, int nb, int N){
    __shared__ unsigned s[256];
    int t = threadIdx.x;
    unsigned v = (t < nb) ? bsum[t] : 0u;
    s[t] = v;
    __syncthreads();
    for (int o = 1; o < 256; o <<= 1){
        unsigned u = (t >= o) ? s[t - o] : 0u;
        __syncthreads();
        s[t] += u;
        __syncthreads();
    }
    if (t < nb) boff[t] = s[t] - v;
    if (t == 0) poff[N] = 32u * s[nb - 1];
}

// ---------------- offsets + self-slot/tail fill ----------------
__global__ void k_offs_fill(const unsigned* __restrict__ cnt, const unsigned* __restrict__ boff,
                            const float* __restrict__ dis,
                            unsigned* __restrict__ poff, int2* __restrict__ sedge, int N){
    int b = blockIdx.x, t = threadIdx.x;
    int i = b * 256 + t;
    unsigned c = (i < N) ? cnt[i] : 0u;
    unsigned v = (i < N) ? ((c + 32u) >> 5) : 0u;
    int lane = t & 63, w = t >> 6;
    unsigned x = v;
    #pragma unroll
    for (int o = 1; o < 64; o <<= 1){
        unsigned u = __shfl_up(x, (unsigned)o, 64);
        if (lane >= o) x += u;
    }
    __shared__ unsigned ws[4];
    if (lane == 63) ws[w] = x;
    __syncthreads();
    unsigned wb = 0;
    if (w > 0) wb += ws[0];
    if (w > 1) wb += ws[1];
    if (w > 2) wb += ws[2];
    if (i < N){
        unsigned p = 32u * (boff[b] + wb + x - v);
        poff[i] = p;
        float dd = dis[i];
        int2 sv = make_int2(i, __float_as_int(dd * dd));
        sedge[p] = sv;
        unsigned s1 = p + 32u * v;
        for (unsigned s = p + 1u + c; s < s1; s++) sedge[s] = sv;
    }
}

// ---------------- ATOMIC-FREE scatter: slot = poff[c] + 1 + rank[e] ----------------
__global__ void k_scatter(const int* __restrict__ row, const int* __restrict__ col,
                          const float* __restrict__ ew, const float* __restrict__ dis,
                          const unsigned* __restrict__ poff, const unsigned* __restrict__ rank,
                          int2* __restrict__ sedge, int E){
    int e = blockIdx.x * blockDim.x + threadIdx.x;
    if (e < E){
        int r = row[e], c = col[e];
        float nw = dis[r] * ew[e] * dis[c];
        unsigned p = poff[c] + 1u + rank[e];
        sedge[p] = make_int2(r, __float_as_int(nw));
    }
}

// ---------------- layer-1 fused linear+max-agg via MFMA ----------------
__global__ __launch_bounds__(256) void k_agg1m(const float* __restrict__ xp,
                                               const unsigned short* __restrict__ W1f,
                                               const unsigned* __restrict__ cnt,
                                               const unsigned* __restrict__ poff,
                                               const int2* __restrict__ sedge,
                                               const float* __restrict__ bias,
                                               float* __restrict__ out, int N, int nwaves){
    int wid  = blockIdx.x * 4 + (threadIdx.x >> 6);
    int lane = threadIdx.x & 63;
    int lm   = lane & 31;

    bf16x8 bh[8], bl[8];
    #pragma unroll
    for (int j = 0; j < 8; j++){
        bh[j] = *(const bf16x8*)(W1f + ((size_t)(0 * 8 + j) * 64 + lane) * 8);
        bl[j] = *(const bf16x8*)(W1f + ((size_t)(1 * 8 + j) * 64 + lane) * 8);
    }
    float bv[8];
    #pragma unroll
    for (int j = 0; j < 8; j++){
        int c = 32 * j + lm;
        bv[j] = (c < HID) ? bias[c] : 0.0f;
    }
    const f32x16 zv = {};

    for (int d = wid; d < N; d += nwaves){
        unsigned base = poff[d];
        unsigned nch  = (cnt[d] + 32u) >> 5;
        float m[8];
        #pragma unroll
        for (int j = 0; j < 8; j++) m[j] = -FLT_MAX;

        for (unsigned c = 0; c < nch; c++){
            u16x8 ahu = (u16x8)0, alu = (u16x8)0;
            if (lane < 32){
                int2 e = sedge[base + 32u * c + (unsigned)lm];
                float w = __int_as_float(e.y);
                const float4* xr = (const float4*)(xp + (size_t)e.x * 8);
                float4 x0 = xr[0], x1 = xr[1];
                float p[5] = {w * x0.x, w * x0.y, w * x0.z, w * x0.w, w * x1.x};
                #pragma unroll
                for (int k = 0; k < 5; k++){
                    unsigned short h = f2b_rne(p[k]);
                    ahu[k] = h;
                    alu[k] = f2b_rne(p[k] - b2f(h));
                }
            }
            bf16x8 ah = __builtin_bit_cast(bf16x8, ahu);
            bf16x8 al = __builtin_bit_cast(bf16x8, alu);
            #pragma unroll
            for (int j = 0; j < 8; j += 2){
                f32x16 a0 = __builtin_amdgcn_mfma_f32_32x32x16_bf16(ah, bh[j],     zv, 0, 0, 0);
                f32x16 a1 = __builtin_amdgcn_mfma_f32_32x32x16_bf16(ah, bh[j + 1], zv, 0, 0, 0);
                a0 = __builtin_amdgcn_mfma_f32_32x32x16_bf16(ah, bl[j],     a0, 0, 0, 0);
                a1 = __builtin_amdgcn_mfma_f32_32x32x16_bf16(ah, bl[j + 1], a1, 0, 0, 0);
                a0 = __builtin_amdgcn_mfma_f32_32x32x16_bf16(al, bh[j],     a0, 0, 0, 0);
                a1 = __builtin_amdgcn_mfma_f32_32x32x16_bf16(al, bh[j + 1], a1, 0, 0, 0);
                m[j]     = fmaxf(m[j],     vmax16(a0));
                m[j + 1] = fmaxf(m[j + 1], vmax16(a1));
            }
        }
        float o[8];
        #pragma unroll
        for (int j = 0; j < 8; j++){
            float other = __shfl_xor(m[j], 32, 64);
            o[j] = fmaxf(fmaxf(m[j], other) + bv[j], 0.0f);
        }
        if (lane < 32){
            float* orow = out + (size_t)d * HID;
            #pragma unroll
            for (int j = 0; j < 8; j++){
                int c = 32 * j + lm;
                if (c < HID) orow[c] = o[j];
            }
        }
    }
}

// ---------------- split-bf16 MFMA GEMM, 64-row tiles: C = A(M x 240) @ W(240 x Ncol) ----------------
// OB16: bf16 rows at stride Cld (=256 -> 512B line-aligned rows for the gather).
// !OB16: fp32 rows of stride Cld with bias.
template <bool OB16>
__global__ __launch_bounds__(256) void k_gemm_mfma(const float* __restrict__ A,
                                                   const unsigned short* __restrict__ Bth,
                                                   const unsigned short* __restrict__ Btl,
                                                   const float* __restrict__ bias,
                                                   void* __restrict__ Cv,
                                                   int M, int Ncol, int Npad, int Cld){
    __shared__ unsigned short As_hi[64][24];
    __shared__ unsigned short As_lo[64][24];
    const int K = 240;
    int t = threadIdx.x;
    int wave = t >> 6, lane = t & 63;
    int m0 = blockIdx.x * 64;
    int n0 = wave * 64;
    bool wact = n0 < Npad;

    int lm   = lane & 31;
    int quad = lane >> 5;

    f32x16 acc[2][2] = {};   // [m-half][n-tile]

    for (int k0 = 0; k0 < K; k0 += 16){
        {
            int m = t >> 2, kq = (t & 3) * 4;   // 64 rows x 4 cols of float4
            float4 av = make_float4(0.f, 0.f, 0.f, 0.f);
            if (m0 + m < M) av = *(const float4*)(A + (size_t)(m0 + m) * K + k0 + kq);
            ushort4 hi, lo;
            hi.x = f2b_rne(av.x); lo.x = f2b_rne(av.x - b2f(hi.x));
            hi.y = f2b_rne(av.y); lo.y = f2b_rne(av.y - b2f(hi.y));
            hi.z = f2b_rne(av.z); lo.z = f2b_rne(av.z - b2f(hi.z));
            hi.w = f2b_rne(av.w); lo.w = f2b_rne(av.w - b2f(hi.w));
            *(ushort4*)&As_hi[m][kq] = hi;
            *(ushort4*)&As_lo[m][kq] = lo;
        }
        __syncthreads();
        if (wact){
            size_t bo0 = (size_t)(n0 + lm) * K + k0 + quad * 8;
            size_t bo1 = (size_t)(n0 + 32 + lm) * K + k0 + quad * 8;
            bf16x8 bh0 = *(const bf16x8*)(Bth + bo0);
            bf16x8 bl0 = *(const bf16x8*)(Btl + bo0);
            bf16x8 bh1 = *(const bf16x8*)(Bth + bo1);
            bf16x8 bl1 = *(const bf16x8*)(Btl + bo1);
            #pragma unroll
            for (int mh = 0; mh < 2; mh++){
                bf16x8 ah = *(const bf16x8*)&As_hi[32 * mh + lm][quad * 8];
                bf16x8 al = *(const bf16x8*)&As_lo[32 * mh + lm][quad * 8];
                acc[mh][0] = __builtin_amdgcn_mfma_f32_32x32x16_bf16(ah, bh0, acc[mh][0], 0, 0, 0);
                acc[mh][0] = __builtin_amdgcn_mfma_f32_32x32x16_bf16(ah, bl0, acc[mh][0], 0, 0, 0);
                acc[mh][0] = __builtin_amdgcn_mfma_f32_32x32x16_bf16(al, bh0, acc[mh][0], 0, 0, 0);
                acc[mh][1] = __builtin_amdgcn_mfma_f32_32x32x16_bf16(ah, bh1, acc[mh][1], 0, 0, 0);
                acc[mh][1] = __builtin_amdgcn_mfma_f32_32x32x16_bf16(ah, bl1, acc[mh][1], 0, 0, 0);
                acc[mh][1] = __builtin_amdgcn_mfma_f32_32x32x16_bf16(al, bh1, acc[mh][1], 0, 0, 0);
            }
        }
        __syncthreads();
    }

    if (!wact) return;
    #pragma unroll
    for (int mh = 0; mh < 2; mh++){
        #pragma unroll
        for (int h = 0; h < 2; h++){
            int n = n0 + 32 * h + lm;
            if (n >= Ncol) continue;
            float bvv = (!OB16 && bias) ? bias[n] : 0.0f;
            #pragma unroll
            for (int r = 0; r < 16; r++){
                int m = m0 + 32 * mh + (r & 3) + 8 * (r >> 2) + 4 * quad;
                if (m >= M) continue;
                float v = acc[mh][h][r];
                if (OB16){
                    ((unsigned short*)Cv)[(size_t)m * Cld + n] = f2b_rne(v);
                } else {
                    ((float*)Cv)[(size_t)m * Cld + n] = v + bvv;
                }
            }
        }
    }
}

// ---------------- FUSED layer-2 scatter-max + readout GEMM ----------------
// Block = 16 targets (4 waves x 4). Phase 1: per-wave gather max-agg (R8 k_aggb structure,
// 113us, unroll-8 over padded bounds) -> +b2, ReLU, split-bf16 into LDS A-tile [16][264]
// (cols 240..263 zeroed; K padded to 256). Phase 2: out[16x80] = A(16x240) @ We(240x80) + be
// via mfma_f32_16x16x32_bf16 (split-bf16: ah*bh + ah*bl + al*bh), 5 col-tiles over 4 waves.
// Saves the 48MB bufB write + 48MB read + the separate readout GEMM launch.
// C/D layout (m89-verified): col = lane&15, row = (lane>>4)*4 + reg.
// Bt3h/Bt3l reads at k>=240 land in the next row (finite We-derived bf16 or zeros) * A=0 -> exact 0.
__global__ __launch_bounds__(256) void k_aggb_f(const unsigned short* __restrict__ H2,
                                                const unsigned* __restrict__ cnt,
                                                const unsigned* __restrict__ poff,
                                                const int2* __restrict__ sedge,
                                                const float* __restrict__ bias,   // b2
                                                const unsigned short* __restrict__ Bt3h,
                                                const unsigned short* __restrict__ Bt3l,
                                                const float* __restrict__ be,
                                                float* __restrict__ out, int N){
    __shared__ unsigned short Ah[16][264];
    __shared__ unsigned short Al[16][264];

    int t    = threadIdx.x;
    int wid  = t >> 6;
    int lane = t & 63;
    int tbase = blockIdx.x * 16;

    // zero the K-pad columns (240..263) for all 16 rows
    for (int i = t; i < 16 * 24; i += 256){
        int r = i / 24, c = 240 + (i % 24);
        Ah[r][c] = 0;
        Al[r][c] = 0;
    }

    // ---- phase 1: gather max-agg for 4 targets per wave ----
    bool act = lane < 60;
    float4 bv = act ? ((const float4*)bias)[lane] : make_float4(0.f, 0.f, 0.f, 0.f);
    #pragma unroll
    for (int i = 0; i < 4; i++){
        int rowi = wid * 4 + i;
        int d = tbase + rowi;
        unsigned p0  = (d < N) ? poff[d] : 0u;
        unsigned ng8 = (d < N) ? ((cnt[d] + 8u) >> 3) : 0u;  // pad slots are self-edges (valid)
        const int2* se = sedge + p0;

        float4 m = make_float4(-FLT_MAX, -FLT_MAX, -FLT_MAX, -FLT_MAX);
        for (unsigned it = 0; it < ng8; it++){
            int2 e0 = se[0], e1 = se[1], e2 = se[2], e3 = se[3];
            int2 e4 = se[4], e5 = se[5], e6 = se[6], e7 = se[7];
            se += 8;
            if (act){
                ushort4 g0 = ((const ushort4*)(H2 + ((size_t)(unsigned)e0.x << 8)))[lane];
                ushort4 g1 = ((const ushort4*)(H2 + ((size_t)(unsigned)e1.x << 8)))[lane];
                ushort4 g2 = ((const ushort4*)(H2 + ((size_t)(unsigned)e2.x << 8)))[lane];
                ushort4 g3 = ((const ushort4*)(H2 + ((size_t)(unsigned)e3.x << 8)))[lane];
                ushort4 g4 = ((const ushort4*)(H2 + ((size_t)(unsigned)e4.x << 8)))[lane];
                ushort4 g5 = ((const ushort4*)(H2 + ((size_t)(unsigned)e5.x << 8)))[lane];
                ushort4 g6 = ((const ushort4*)(H2 + ((size_t)(unsigned)e6.x << 8)))[lane];
                ushort4 g7 = ((const ushort4*)(H2 + ((size_t)(unsigned)e7.x << 8)))[lane];
                float w0 = __int_as_float(e0.y), w1 = __int_as_float(e1.y);
                float w2 = __int_as_float(e2.y), w3 = __int_as_float(e3.y);
                float w4 = __int_as_float(e4.y), w5 = __int_as_float(e5.y);
                float w6 = __int_as_float(e6.y), w7 = __int_as_float(e7.y);
                m.x = max3f(max3f(w0*b2f(g0.x), w1*b2f(g1.x), w2*b2f(g2.x)),
                            max3f(w3*b2f(g3.x), w4*b2f(g4.x), w5*b2f(g5.x)),
                            max3f(w6*b2f(g6.x), w7*b2f(g7.x), m.x));
                m.y = max3f(max3f(w0*b2f(g0.y), w1*b2f(g1.y), w2*b2f(g2.y)),
                            max3f(w3*b2f(g3.y), w4*b2f(g4.y), w5*b2f(g5.y)),
                            max3f(w6*b2f(g6.y), w7*b2f(g7.y), m.y));
                m.z = max3f(max3f(w0*b2f(g0.z), w1*b2f(g1.z), w2*b2f(g2.z)),
                            max3f(w3*b2f(g3.z), w4*b2f(g4.z), w5*b2f(g5.z)),
                            max3f(w6*b2f(g6.z), w7*b2f(g7.z), m.z));
                m.w = max3f(max3f(w0*b2f(g0.w), w1*b2f(g1.w), w2*b2f(g2.w)),
                            max3f(w3*b2f(g3.w), w4*b2f(g4.w), w5*b2f(g5.w)),
                            max3f(w6*b2f(g6.w), w7*b2f(g7.w), m.w));
            }
        }
        if (act && (d < N)){
            float o0 = fmaxf(m.x + bv.x, 0.0f);
            float o1 = fmaxf(m.y + bv.y, 0.0f);
            float o2 = fmaxf(m.z + bv.z, 0.0f);
            float o3 = fmaxf(m.w + bv.w, 0.0f);
            ushort4 hi, lo;
            hi.x = f2b_rne(o0); lo.x = f2b_rne(o0 - b2f(hi.x));
            hi.y = f2b_rne(o1); lo.y = f2b_rne(o1 - b2f(hi.y));
            hi.z = f2b_rne(o2); lo.z = f2b_rne(o2 - b2f(hi.z));
            hi.w = f2b_rne(o3); lo.w = f2b_rne(o3 - b2f(hi.w));
            *(ushort4*)&Ah[rowi][lane * 4] = hi;
            *(ushort4*)&Al[rowi][lane * 4] = lo;
        } else if (act){
            // d >= N: write zeros so the A row is finite (C row is discarded at store)
            ushort4 z = make_ushort4(0, 0, 0, 0);
            *(ushort4*)&Ah[rowi][lane * 4] = z;
            *(ushort4*)&Al[rowi][lane * 4] = z;
        }
    }
    __syncthreads();

    // ---- phase 2: out(16x80) = A @ We + be, 5 col-tiles of 16 over 4 waves ----
    int arow = lane & 15;
    int kgrp = (lane >> 4) * 8;
    for (int tile = wid; tile < 5; tile += 4){
        int n0 = tile * 16;
        int coln = n0 + (lane & 15);          // < 80 always (max 79)
        f32x4 acc = {};
        #pragma unroll
        for (int kk = 0; kk < 256; kk += 32){
            bf16x8 ah = *(const bf16x8*)&Ah[arow][kk + kgrp];
            bf16x8 al = *(const bf16x8*)&Al[arow][kk + kgrp];
            bf16x8 bh = *(const bf16x8*)(Bt3h + (size_t)coln * 240 + kk + kgrp);
            bf16x8 bl = *(const bf16x8*)(Bt3l + (size_t)coln * 240 + kk + kgrp);
            acc = __builtin_amdgcn_mfma_f32_16x16x32_bf16(ah, bh, acc, 0, 0, 0);
            acc = __builtin_amdgcn_mfma_f32_16x16x32_bf16(ah, bl, acc, 0, 0, 0);
            acc = __builtin_amdgcn_mfma_f32_16x16x32_bf16(al, bh, acc, 0, 0, 0);
        }
        float bev = be[coln];
        #pragma unroll
        for (int r = 0; r < 4; r++){
            int mrow = (lane >> 4) * 4 + r;
            int d2 = tbase + mrow;
            if (d2 < N)
                out[(size_t)d2 * 80 + coln] = acc[r] + bev;
        }
    }
}

extern "C" void kernel_launch(void* const* d_in, const int* in_sizes, int n_in,
                              void* d_out, int out_size, void* d_ws, size_t ws_size,
                              hipStream_t stream){
    const float* x  = (const float*)d_in[0];
    const int*   ei = (const int*)  d_in[1];
    const float* ew = (const float*)d_in[2];
    const float* W1 = (const float*)d_in[3];
    const float* b1 = (const float*)d_in[4];
    const float* W2 = (const float*)d_in[5];
    const float* b2 = (const float*)d_in[6];
    const float* We = (const float*)d_in[7];
    const float* be = (const float*)d_in[8];
    float* out = (float*)d_out;

    const int N = in_sizes[0] / 5;
    const int E = in_sizes[2];
    const int* row = ei;
    const int* col = ei + E;
    const int nb = (N + 255) / 256;

    char* w = (char*)d_ws;
    size_t o = 0;
    auto alloc = [&](size_t bytes) -> void* {
        void* p = w + o;
        o = alignUp(o + bytes, 256);
        return p;
    };
    unsigned long long* pk = (unsigned long long*) alloc((size_t)N * 8);
    float*          dis   = (float*)          alloc((size_t)N * 4);
    unsigned*       cnt   = (unsigned*)       alloc((size_t)N * 4);
    unsigned*       poff  = (unsigned*)       alloc((size_t)(N + 1) * 4);
    unsigned*       bsum  = (unsigned*)       alloc((size_t)nb * 4);
    unsigned*       boff  = (unsigned*)       alloc((size_t)nb * 4);
    unsigned*       rank  = (unsigned*)       alloc((size_t)E * 4);
    int2*           sedge = (int2*)           alloc(((size_t)E + 32u * N + 64u) * 8);
    float*          xp    = (float*)          alloc((size_t)N * 8 * 4);
    unsigned short* W1f   = (unsigned short*) alloc((size_t)2 * 8 * 64 * 8 * 2);
    unsigned short* Bt2h  = (unsigned short*) alloc((size_t)256 * HID * 2);
    unsigned short* Bt2l  = (unsigned short*) alloc((size_t)256 * HID * 2);
    unsigned short* Bt3h  = (unsigned short*) alloc((size_t)128 * HID * 2);
    unsigned short* Bt3l  = (unsigned short*) alloc((size_t)128 * HID * 2);
    unsigned short* bufH2 = (unsigned short*) alloc((size_t)N * 256 * 2);   // 512B-aligned rows
    float*          bufB  = (float*)          alloc((size_t)N * HID * 4);
    (void)ws_size; (void)n_in; (void)out_size;

    int ne = (E + 255) / 256;

    // graph build; independent weight/x prep rides the atomic-bound launch for free
    hipMemsetAsync(pk, 0, (size_t)N * 8, stream);
    k_deg_prep <<<ne + nb + 32 + 240 + 120, 256, 0, stream>>>(col, ew, pk, rank, E, ne, N, nb,
                                                              x, xp, W1, W1f,
                                                              W2, Bt2h, Bt2l,
                                                              We, Bt3h, Bt3l);
    k_dis_bsum <<<nb, 256, 0, stream>>>(pk, dis, cnt, bsum, N);
    k_bscan    <<<1, 256, 0, stream>>>(bsum, boff, poff, nb, N);
    k_offs_fill<<<nb, 256, 0, stream>>>(cnt, boff, dis, poff, sedge, N);
    k_scatter  <<<ne, 256, 0, stream>>>(row, col, ew, dis, poff, rank, sedge, E);

    // layer 1: MFMA fused linear + max-agg + b1 + ReLU
    const int a1blocks = 1536;
    k_agg1m<<<a1blocks, 256, 0, stream>>>(xp, W1f, cnt, poff, sedge, b1, bufB, N, a1blocks * 4);

    // layer 2: split-bf16 MFMA GEMM (64-row tiles) -> bf16 rows (stride 256)
    int gm = (N + 63) / 64;
    k_gemm_mfma<true><<<gm, 256, 0, stream>>>(bufB, Bt2h, Bt2l, nullptr, bufH2, N, HID, 256, 256);

    // fused: layer-2 gather max-agg + b2 + ReLU + readout GEMM (+be) -> out
    k_aggb_f<<<(N + 15) / 16, 256, 0, stream>>>(bufH2, cnt, poff, sedge, b2,
                                                Bt3h, Bt3l, be, out, N);
}